// Round 7
// baseline (1175.333 us; speedup 1.0000x reference)
//
#include <hip/hip_runtime.h>

#define BB 4096
#define TT 200
// E = H = 64

typedef unsigned short u16;
typedef unsigned int   u32;
typedef unsigned short u16x8 __attribute__((ext_vector_type(8)));
typedef short s16x8 __attribute__((ext_vector_type(8)));
typedef float f32x4 __attribute__((ext_vector_type(4)));

__device__ __forceinline__ float bf2f(u16 u){ union{unsigned u; float f;} v; v.u=((unsigned)u)<<16; return v.f; }
__device__ __forceinline__ u16 f2bf(float f){ union{float f; unsigned u;} v; v.f=f; unsigned r=v.u + 0x7FFFu + ((v.u>>16)&1u); return (u16)(r>>16); }
__device__ __forceinline__ float sigm(float x){ return 1.0f/(1.0f+__expf(-x)); }
__device__ __forceinline__ float tanh_(float x){ return 1.0f - 2.0f/(1.0f+__expf(2.0f*x)); }

#define MFMA16(a,b,c) __builtin_amdgcn_mfma_f32_16x16x32_bf16((a),(b),(c),0,0,0)

// split fp32 octet into bf16 hi (truncate) + lo (RNE remainder): ~24-bit accuracy through MFMA
// NOTE: scalar form. R6 measured v_cvt_pk_bf16_f32 as a VALU-throughput regression — keep scalar.
__device__ __forceinline__ void split8(const f32x4 a, const f32x4 b, s16x8 &hi, s16x8 &lo){
#pragma unroll
  for (int j=0;j<4;j++){
    float v=a[j]; u16 h=(u16)(__float_as_uint(v)>>16);
    hi[j]=(short)h; lo[j]=(short)f2bf(v-bf2f(h));
    v=b[j]; h=(u16)(__float_as_uint(v)>>16);
    hi[j+4]=(short)h; lo[j+4]=(short)f2bf(v-bf2f(h));
  }
}

// ================================================================
// FAST PATH: hist_sum || scan1 -> attn(+softmax) -> scan2 -> fcn
// Scans: 8 batch rows/block (MFMA rows 8-15 duplicate 0-7, discarded)
// -> 512 blocks = 2 blocks/CU for latency overlap.
// ================================================================

// ---------------- hist_sum (unmasked, parallel) ----------------
__global__ void hist_sum_kernel(const int* __restrict__ hist, const float* __restrict__ emb,
                                float* __restrict__ hs){
  int tid = blockIdx.x*256 + threadIdx.x;     // B*8 threads
  int b = tid>>3, cg = (tid&7)*8;
  float acc[8];
#pragma unroll
  for (int j=0;j<8;j++) acc[j]=0.0f;
  for (int t=0;t<TT;t++){
    int idx = hist[(size_t)b*TT+t];
    f32x4 v0=*(const f32x4*)(emb+(size_t)idx*64+cg);
    f32x4 v1=*(const f32x4*)(emb+(size_t)idx*64+cg+4);
#pragma unroll
    for (int j=0;j<4;j++){ acc[j]+=v0[j]; acc[j+4]+=v1[j]; }
  }
#pragma unroll
  for (int j=0;j<8;j++) hs[(size_t)b*64+cg+j]=acc[j];
}

// ---------------- scan1: gru1, 4-wave N-split, 8 rows/block ----------------
__global__ __launch_bounds__(256,2) void scan1_kernel(
    const int* __restrict__ hist, const float* __restrict__ mask, const float* __restrict__ emb,
    const float* __restrict__ Wg, const float* __restrict__ Ug, const float* __restrict__ bg,
    const float* __restrict__ Wc, const float* __restrict__ Uc, const float* __restrict__ bc,
    int* __restrict__ len_g, u16* __restrict__ rnn1)
{
  __shared__ float h1buf[16][68];
  __shared__ float pbuf [16][68];
  __shared__ int   lenL [16];
  const int tid=threadIdx.x;
  const int w=tid>>6, lane=tid&63, q=lane>>4, mm=lane&15;
  const int g=blockIdx.x, b0=g*8, pb_m=b0+(mm&7);   // rows 8-15 duplicate 0-7

  if (w==0){
    int cnt=0;
    for (int t=q*50;t<q*50+50;t++) cnt += (mask[(size_t)pb_m*TT+t]!=0.0f);
    cnt += __shfl_xor(cnt,16);
    cnt += __shfl_xor(cnt,32);
    if (lane<16) lenL[lane]=cnt;
    if (lane<8)  len_g[b0+lane]=cnt;
  }
  for (int ii=tid; ii<16*68; ii+=256) (&h1buf[0][0])[ii]=0.0f;
  __syncthreads();

  int lenq[4];
#pragma unroll
  for (int r=0;r<4;r++) lenq[r]=lenL[q*4+r];
  int maxlen=1;
  for (int i=0;i<8;i++) maxlen=(lenL[i]>maxlen)?lenL[i]:maxlen;

  const int nr=16*w+mm, nz=64+16*w+mm;
  s16x8 wgr[4], wgz[4], wcf[4];
#pragma unroll
  for (int c=0;c<4;c++){
    s16x8 fr,fz,fc;
#pragma unroll
    for (int j=0;j<8;j++){
      int k=32*c+q*8+j;
      fr[j]=(short)f2bf((k<64)?Wg[(size_t)k*128+nr]:Ug[(size_t)(k-64)*128+nr]);
      fz[j]=(short)f2bf((k<64)?Wg[(size_t)k*128+nz]:Ug[(size_t)(k-64)*128+nz]);
      fc[j]=(short)f2bf((k<64)?Wc[(size_t)k*64+nr]:Uc[(size_t)(k-64)*64+nr]);
    }
    wgr[c]=fr; wgz[c]=fz; wcf[c]=fc;
  }
  const float bgr=bg[nr], bgz=bg[nz], bcv=bc[nr];

  auto load_x=[&](int t, s16x8 &a0, s16x8 &a1){
    int idx = hist[(size_t)pb_m*TT+t];
    const float* p=emb+(size_t)idx*64;
    f32x4 v0=*(const f32x4*)(p+q*8),    v1=*(const f32x4*)(p+q*8+4);
    f32x4 v2=*(const f32x4*)(p+32+q*8), v3=*(const f32x4*)(p+32+q*8+4);
    s16x8 t0,t1;
#pragma unroll
    for (int j=0;j<4;j++){
      t0[j]=(short)f2bf(v0[j]); t0[j+4]=(short)f2bf(v1[j]);
      t1[j]=(short)f2bf(v2[j]); t1[j+4]=(short)f2bf(v3[j]);
    }
    a0=t0; a1=t1;
  };

  s16x8 xf0,xf1;
  load_x(0,xf0,xf1);
  for (int t=0;t<maxlen;t++){
    s16x8 nx0,nx1;
    { int tn=(t+1<maxlen)?(t+1):(maxlen-1); load_x(tn,nx0,nx1); }

    f32x4 hA0=*(const f32x4*)&h1buf[mm][q*8];
    f32x4 hA1=*(const f32x4*)&h1buf[mm][q*8+4];
    f32x4 hB0=*(const f32x4*)&h1buf[mm][32+q*8];
    f32x4 hB1=*(const f32x4*)&h1buf[mm][32+q*8+4];
    s16x8 hhi0,hlo0,hhi1,hlo1;
    split8(hA0,hA1,hhi0,hlo0);
    split8(hB0,hB1,hhi1,hlo1);

    f32x4 ar={0.0f,0.0f,0.0f,0.0f}, az={0.0f,0.0f,0.0f,0.0f};
    ar=MFMA16(xf0 ,wgr[0],ar); az=MFMA16(xf0 ,wgz[0],az);
    ar=MFMA16(xf1 ,wgr[1],ar); az=MFMA16(xf1 ,wgz[1],az);
    ar=MFMA16(hhi0,wgr[2],ar); az=MFMA16(hhi0,wgz[2],az);
    ar=MFMA16(hhi1,wgr[3],ar); az=MFMA16(hhi1,wgz[3],az);
    ar=MFMA16(hlo0,wgr[2],ar); az=MFMA16(hlo0,wgz[2],az);
    ar=MFMA16(hlo1,wgr[3],ar); az=MFMA16(hlo1,wgz[3],az);

    float zs[4], hv[4];
#pragma unroll
    for (int r=0;r<4;r++){
      float rg=sigm(ar[r]+bgr);
      float hp=h1buf[q*4+r][16*w+mm];
      hv[r]=hp;
      pbuf[q*4+r][16*w+mm]=rg*hp;
      zs[r]=sigm(az[r]+bgz);
    }
    __syncthreads();

    f32x4 pA0=*(const f32x4*)&pbuf[mm][q*8];
    f32x4 pA1=*(const f32x4*)&pbuf[mm][q*8+4];
    f32x4 pB0=*(const f32x4*)&pbuf[mm][32+q*8];
    f32x4 pB1=*(const f32x4*)&pbuf[mm][32+q*8+4];
    s16x8 phi0,plo0,phi1,plo1;
    split8(pA0,pA1,phi0,plo0);
    split8(pB0,pB1,phi1,plo1);

    f32x4 ac={0.0f,0.0f,0.0f,0.0f};
    ac=MFMA16(xf0 ,wcf[0],ac);
    ac=MFMA16(xf1 ,wcf[1],ac);
    ac=MFMA16(phi0,wcf[2],ac);
    ac=MFMA16(phi1,wcf[3],ac);
    ac=MFMA16(plo0,wcf[2],ac);
    ac=MFMA16(plo1,wcf[3],ac);
#pragma unroll
    for (int r=0;r<4;r++){
      float c=tanh_(ac[r]+bcv);
      float z=zs[r];
      float hn=z*hv[r]+(1.0f-z)*c;
      if (t>=lenq[r]) hn=hv[r];
      h1buf[q*4+r][16*w+mm]=hn;
      if (q<2) rnn1[((size_t)(b0+q*4+r)*TT+t)*64 + 16*w+mm]=f2bf(hn);
    }
    __syncthreads();
    xf0=nx0; xf1=nx1;
  }
}

// ---------------- attn + fused masked softmax: 1 wave per batch row ----------------
// regroup: [q,k,q-k,q*k]@Wa1 = pre + k@(B-C) + (q.*k)@D ; pre = q@(A+C)+ba1
__global__ __launch_bounds__(64,1) void attn_kernel(
    const int* __restrict__ iidx, const float* __restrict__ emb, const u16* __restrict__ rnn1,
    const float* __restrict__ Wa1, const float* __restrict__ ba1,
    const float* __restrict__ Wa2, const float* __restrict__ ba2,
    const float* __restrict__ Wa3, const float* __restrict__ ba3,
    const int* __restrict__ len_g, float* __restrict__ alph)
{
  __shared__ u16 d1buf[16][104];   // cols 80..95 stay zero (K-pad for layer2)
  __shared__ float scS[208];
  const int lane=threadIdx.x, q=lane>>4, mm=lane&15;
  const int b=blockIdx.x;
  const int L=len_g[b];

  s16x8 w1k[5][2], wd[5][2];
#pragma unroll
  for (int nt=0;nt<5;nt++)
#pragma unroll
    for (int c=0;c<2;c++){
      s16x8 f1,f2;
#pragma unroll
      for (int j=0;j<8;j++){
        int k=32*c+q*8+j, n=16*nt+mm;
        f1[j]=(short)f2bf(Wa1[(size_t)(64+k)*80+n] - Wa1[(size_t)(128+k)*80+n]);
        f2[j]=(short)f2bf(Wa1[(size_t)(192+k)*80+n]);
      }
      w1k[nt][c]=f1; wd[nt][c]=f2;
    }
  s16x8 w2f[3][3];
#pragma unroll
  for (int nt=0;nt<3;nt++)
#pragma unroll
    for (int c=0;c<3;c++){
      s16x8 f;
#pragma unroll
      for (int j=0;j<8;j++){
        int k=32*c+q*8+j, n=16*nt+mm;
        f[j]=(short)((k<80 && n<40)?f2bf(Wa2[(size_t)k*40+n]):0);
      }
      w2f[nt][c]=f;
    }
  float ba2v[3], w3v[3];
#pragma unroll
  for (int nt=0;nt<3;nt++){ int n=16*nt+mm; ba2v[nt]=(n<40)?ba2[n]:0.0f; w3v[nt]=(n<40)?Wa3[n]:0.0f; }
  const float ba3v=ba3[0];

  const int ib=iidx[b];
  float qv0[8], qv1[8];
  s16x8 aq0,aq1;
#pragma unroll
  for (int j=0;j<8;j++){
    qv0[j]=emb[(size_t)ib*64+q*8+j];
    qv1[j]=emb[(size_t)ib*64+32+q*8+j];
    aq0[j]=(short)f2bf(qv0[j]); aq1[j]=(short)f2bf(qv1[j]);
  }
  float pre[5];
#pragma unroll
  for (int nt=0;nt<5;nt++){
    int n=16*nt+mm;
    s16x8 bp0,bp1;
#pragma unroll
    for (int j=0;j<8;j++){
      int k=q*8+j, k2=32+q*8+j;
      bp0[j]=(short)f2bf(Wa1[(size_t)k *80+n]+Wa1[(size_t)(128+k )*80+n]);
      bp1[j]=(short)f2bf(Wa1[(size_t)k2*80+n]+Wa1[(size_t)(128+k2)*80+n]);
    }
    f32x4 a={0.0f,0.0f,0.0f,0.0f};
    a=MFMA16(aq0,bp0,a); a=MFMA16(aq1,bp1,a);
    pre[nt]=a[0]+ba1[n];
  }

  for (int ii=lane; ii<16*104; ii+=64) (&d1buf[0][0])[ii]=0;
  for (int t=lane;t<208;t+=64) scS[t]=-1e9f;
  __syncthreads();

  const int nch=(L+15)>>4;
  for (int ch=0; ch<nch; ch++){
    int t0=ch*16;
    size_t base=((size_t)b*TT + t0+mm)*64;
    s16x8 kf0=*(const s16x8*)(rnn1+base+q*8);
    s16x8 kf1=*(const s16x8*)(rnn1+base+32+q*8);
    s16x8 kq0,kq1;
#pragma unroll
    for (int j=0;j<8;j++){
      kq0[j]=(short)f2bf(bf2f((u16)kf0[j])*qv0[j]);
      kq1[j]=(short)f2bf(bf2f((u16)kf1[j])*qv1[j]);
    }
    f32x4 acc[5];
#pragma unroll
    for (int nt=0;nt<5;nt++){
      f32x4 a={pre[nt],pre[nt],pre[nt],pre[nt]};
      a=MFMA16(kf0,w1k[nt][0],a); a=MFMA16(kf1,w1k[nt][1],a);
      a=MFMA16(kq0,wd[nt][0],a);  a=MFMA16(kq1,wd[nt][1],a);
      acc[nt]=a;
    }
#pragma unroll
    for (int nt=0;nt<5;nt++)
#pragma unroll
      for (int r=0;r<4;r++)
        d1buf[q*4+r][16*nt+mm]=f2bf(sigm(acc[nt][r]));
    __syncthreads();
    s16x8 a0=*(const s16x8*)&d1buf[mm][q*8];
    s16x8 a1=*(const s16x8*)&d1buf[mm][32+q*8];
    s16x8 a2=*(const s16x8*)&d1buf[mm][64+q*8];
    f32x4 acc2[3];
#pragma unroll
    for (int nt=0;nt<3;nt++){
      f32x4 a={0.0f,0.0f,0.0f,0.0f};
      a=MFMA16(a0,w2f[nt][0],a); a=MFMA16(a1,w2f[nt][1],a); a=MFMA16(a2,w2f[nt][2],a);
      acc2[nt]=a;
    }
    float part[4];
#pragma unroll
    for (int r=0;r<4;r++){
      float s=0.0f;
#pragma unroll
      for (int nt=0;nt<3;nt++) s+=sigm(acc2[nt][r]+ba2v[nt])*w3v[nt];
      part[r]=s;
    }
#pragma unroll
    for (int d=1;d<16;d<<=1)
#pragma unroll
      for (int r=0;r<4;r++) part[r]+=__shfl_xor(part[r],d);
    if (mm==0){
#pragma unroll
      for (int r=0;r<4;r++){ int t=t0+q*4+r; scS[t]=(t<L)?(part[r]+ba3v):-1e9f; }
    }
    __syncthreads();
  }

  // fused masked softmax -> alpha
  float mx=-3e38f;
  for (int t=lane;t<TT;t+=64) mx=fmaxf(mx,scS[t]);
#pragma unroll
  for (int d=1;d<64;d<<=1) mx=fmaxf(mx,__shfl_xor(mx,d));
  float sm=0.0f;
  for (int t=lane;t<TT;t+=64) sm+=__expf(scS[t]-mx);
#pragma unroll
  for (int d=1;d<64;d<<=1) sm+=__shfl_xor(sm,d);
  float inv=1.0f/sm;
  for (int t=lane;t<TT;t+=64){
    float v=(t<L)?__expf(scS[t]-mx)*inv:0.0f;
    alph[(size_t)b*TT+t]=v;
  }
}

// ---------------- scan2: gru2, 4-wave N-split, 8 rows/block, x = rnn1*alpha ----------------
__global__ __launch_bounds__(256,2) void scan2_kernel(
    const u16* __restrict__ rnn1, const float* __restrict__ alpha, const int* __restrict__ len_g,
    const float* __restrict__ Wg, const float* __restrict__ Ug, const float* __restrict__ bg,
    const float* __restrict__ Wc, const float* __restrict__ Uc, const float* __restrict__ bc,
    float* __restrict__ f2)
{
  __shared__ float h2buf[16][68];
  __shared__ float pbuf [16][68];
  __shared__ int   lenL [16];
  const int tid=threadIdx.x;
  const int w=tid>>6, lane=tid&63, q=lane>>4, mm=lane&15;
  const int g=blockIdx.x, b0=g*8, pb_m=b0+(mm&7);

  if (tid<16) lenL[tid]=len_g[b0+(tid&7)];
  for (int ii=tid; ii<16*68; ii+=256) (&h2buf[0][0])[ii]=0.0f;
  __syncthreads();

  int lenq[4];
#pragma unroll
  for (int r=0;r<4;r++) lenq[r]=lenL[q*4+r];
  int maxlen=1;
  for (int i=0;i<8;i++) maxlen=(lenL[i]>maxlen)?lenL[i]:maxlen;

  const int nr=16*w+mm, nz=64+16*w+mm;
  s16x8 wgr[4], wgz[4], wcf[4];
#pragma unroll
  for (int c=0;c<4;c++){
    s16x8 fr,fz,fc;
#pragma unroll
    for (int j=0;j<8;j++){
      int k=32*c+q*8+j;
      fr[j]=(short)f2bf((k<64)?Wg[(size_t)k*128+nr]:Ug[(size_t)(k-64)*128+nr]);
      fz[j]=(short)f2bf((k<64)?Wg[(size_t)k*128+nz]:Ug[(size_t)(k-64)*128+nz]);
      fc[j]=(short)f2bf((k<64)?Wc[(size_t)k*64+nr]:Uc[(size_t)(k-64)*64+nr]);
    }
    wgr[c]=fr; wgz[c]=fz; wcf[c]=fc;
  }
  const float bgr=bg[nr], bgz=bg[nz], bcv=bc[nr];

  auto load_x=[&](int t, s16x8 &a0, s16x8 &a1){
    size_t base=((size_t)pb_m*TT+t)*64;
    u16x8 k0=*(const u16x8*)(rnn1+base+q*8);
    u16x8 k1=*(const u16x8*)(rnn1+base+32+q*8);
    float al=alpha[(size_t)pb_m*TT+t];
    s16x8 t0,t1;
#pragma unroll
    for (int j=0;j<8;j++){
      t0[j]=(short)f2bf(bf2f(k0[j])*al);
      t1[j]=(short)f2bf(bf2f(k1[j])*al);
    }
    a0=t0; a1=t1;
  };

  s16x8 xf0,xf1;
  load_x(0,xf0,xf1);
  for (int t=0;t<maxlen;t++){
    s16x8 nx0,nx1;
    { int tn=(t+1<maxlen)?(t+1):(maxlen-1); load_x(tn,nx0,nx1); }

    f32x4 hA0=*(const f32x4*)&h2buf[mm][q*8];
    f32x4 hA1=*(const f32x4*)&h2buf[mm][q*8+4];
    f32x4 hB0=*(const f32x4*)&h2buf[mm][32+q*8];
    f32x4 hB1=*(const f32x4*)&h2buf[mm][32+q*8+4];
    s16x8 hhi0,hlo0,hhi1,hlo1;
    split8(hA0,hA1,hhi0,hlo0);
    split8(hB0,hB1,hhi1,hlo1);

    f32x4 ar={0.0f,0.0f,0.0f,0.0f}, az={0.0f,0.0f,0.0f,0.0f};
    ar=MFMA16(xf0 ,wgr[0],ar); az=MFMA16(xf0 ,wgz[0],az);
    ar=MFMA16(xf1 ,wgr[1],ar); az=MFMA16(xf1 ,wgz[1],az);
    ar=MFMA16(hhi0,wgr[2],ar); az=MFMA16(hhi0,wgz[2],az);
    ar=MFMA16(hhi1,wgr[3],ar); az=MFMA16(hhi1,wgz[3],az);
    ar=MFMA16(hlo0,wgr[2],ar); az=MFMA16(hlo0,wgz[2],az);
    ar=MFMA16(hlo1,wgr[3],ar); az=MFMA16(hlo1,wgz[3],az);

    float zs[4], hv[4];
#pragma unroll
    for (int r=0;r<4;r++){
      float rg=sigm(ar[r]+bgr);
      float hp=h2buf[q*4+r][16*w+mm];
      hv[r]=hp;
      pbuf[q*4+r][16*w+mm]=rg*hp;
      zs[r]=sigm(az[r]+bgz);
    }
    __syncthreads();

    f32x4 pA0=*(const f32x4*)&pbuf[mm][q*8];
    f32x4 pA1=*(const f32x4*)&pbuf[mm][q*8+4];
    f32x4 pB0=*(const f32x4*)&pbuf[mm][32+q*8];
    f32x4 pB1=*(const f32x4*)&pbuf[mm][32+q*8+4];
    s16x8 phi0,plo0,phi1,plo1;
    split8(pA0,pA1,phi0,plo0);
    split8(pB0,pB1,phi1,plo1);

    f32x4 ac={0.0f,0.0f,0.0f,0.0f};
    ac=MFMA16(xf0 ,wcf[0],ac);
    ac=MFMA16(xf1 ,wcf[1],ac);
    ac=MFMA16(phi0,wcf[2],ac);
    ac=MFMA16(phi1,wcf[3],ac);
    ac=MFMA16(plo0,wcf[2],ac);
    ac=MFMA16(plo1,wcf[3],ac);
#pragma unroll
    for (int r=0;r<4;r++){
      float c=tanh_(ac[r]+bcv);
      float z=zs[r];
      float hn=z*hv[r]+(1.0f-z)*c;
      if (t>=lenq[r]) hn=hv[r];
      h2buf[q*4+r][16*w+mm]=hn;
    }
    __syncthreads();
    xf0=nx0; xf1=nx1;
  }

#pragma unroll
  for (int r=0;r<4;r++)
    if (q<2) f2[(size_t)(b0+q*4+r)*64 + 16*w+mm]=h2buf[q*4+r][16*w+mm];
}

// ---------------- fcn: [ue|ie|hs|ie*hs|f2] (320) -> 128 -> 40 -> 1 ----------------
__global__ __launch_bounds__(64,1) void fcn_kernel(
    const int* __restrict__ uidx, const int* __restrict__ iidx,
    const float* __restrict__ uemb, const float* __restrict__ emb,
    const float* __restrict__ hs, const float* __restrict__ f2,
    const float* __restrict__ Wf1, const float* __restrict__ fb1, const float* __restrict__ fp1,
    const float* __restrict__ Wf2, const float* __restrict__ fb2, const float* __restrict__ fp2,
    const float* __restrict__ Wf3, const float* __restrict__ fb3,
    float* __restrict__ out)
{
  __shared__ float inL[16][320];
  __shared__ u16   h1L[16][128];
  __shared__ float h2o[16][40];
  const int lane=threadIdx.x, q=lane>>4, mm=lane&15;
  const int b0=blockIdx.x*16;

  {
    int row=lane>>2, sub=lane&3;
    int b=b0+row;
    int ub=uidx[b], ibv=iidx[b];
    for (int c=sub*80;c<sub*80+80;c++){
      int seg=c>>6, f=c&63; float v;
      if      (seg==0) v=uemb[(size_t)ub*64+f];
      else if (seg==1) v=emb[(size_t)ibv*64+f];
      else if (seg==2) v=hs[(size_t)b*64+f];
      else if (seg==3) v=emb[(size_t)ibv*64+f]*hs[(size_t)b*64+f];
      else             v=f2[(size_t)b*64+f];
      inL[row][c]=v;
    }
  }
  __syncthreads();

  {
    f32x4 acc1[8];
#pragma unroll
    for (int nt=0;nt<8;nt++) acc1[nt]=f32x4{0.0f,0.0f,0.0f,0.0f};
#pragma unroll
    for (int kc=0;kc<10;kc++){
      s16x8 af;
#pragma unroll
      for (int j=0;j<8;j++) af[j]=(short)f2bf(inL[mm][32*kc+q*8+j]);
#pragma unroll
      for (int nt=0;nt<8;nt++){
        s16x8 bfr;
#pragma unroll
        for (int j=0;j<8;j++) bfr[j]=(short)f2bf(Wf1[(size_t)(32*kc+q*8+j)*128 + 16*nt+mm]);
        acc1[nt]=MFMA16(af,bfr,acc1[nt]);
      }
    }
#pragma unroll
    for (int nt=0;nt<8;nt++)
#pragma unroll
      for (int r=0;r<4;r++){
        int col=16*nt+mm, row=q*4+r;
        float x=acc1[nt][r]+fb1[col];
        float pp=fp1[col];
        h1L[row][col]=f2bf((x>=0.0f)?x:pp*x);
      }
  }
  __syncthreads();

  {
    f32x4 acc2[3];
#pragma unroll
    for (int nt=0;nt<3;nt++) acc2[nt]=f32x4{0.0f,0.0f,0.0f,0.0f};
#pragma unroll
    for (int kc=0;kc<4;kc++){
      s16x8 af=*(const s16x8*)&h1L[mm][32*kc+q*8];
#pragma unroll
      for (int nt=0;nt<3;nt++){
        s16x8 bfr;
#pragma unroll
        for (int j=0;j<8;j++){
          int k=32*kc+q*8+j, n=16*nt+mm;
          bfr[j]=(short)((n<40)?f2bf(Wf2[(size_t)k*40+n]):0);
        }
        acc2[nt]=MFMA16(af,bfr,acc2[nt]);
      }
    }
#pragma unroll
    for (int nt=0;nt<3;nt++)
#pragma unroll
      for (int r=0;r<4;r++){
        int col=16*nt+mm, row=q*4+r;
        if (col<40){
          float x=acc2[nt][r]+fb2[col];
          float pp=fp2[col];
          h2o[row][col]=(x>=0.0f)?x:pp*x;
        }
      }
  }
  __syncthreads();

  {
    int row=lane>>2, sub=lane&3;
    float s=0.0f;
    for (int k=sub;k<40;k+=4) s+=h2o[row][k]*Wf3[k];
    s+=__shfl_xor(s,1); s+=__shfl_xor(s,2);
    if (sub==0) out[b0+row]=s+fb3[0];
  }
}

// ================================================================
// FALLBACK (zero workspace): the R4 mega kernel, f32 path proven
// ================================================================
template<bool F32>
__global__ __launch_bounds__(64,1) void dien_mega_kernel(
    const int* __restrict__ uidx, const int* __restrict__ iidx,
    const int* __restrict__ hist, const void* __restrict__ mask,
    const void* __restrict__ emb,  const void* __restrict__ uemb,
    const void* __restrict__ W1g, const void* __restrict__ U1g, const void* __restrict__ g1bg,
    const void* __restrict__ W1c, const void* __restrict__ U1c, const void* __restrict__ g1bc,
    const void* __restrict__ Wa1, const void* __restrict__ ba1,
    const void* __restrict__ Wa2, const void* __restrict__ ba2,
    const void* __restrict__ Wa3, const void* __restrict__ ba3,
    const void* __restrict__ W2g, const void* __restrict__ U2g, const void* __restrict__ g2bg,
    const void* __restrict__ W2c, const void* __restrict__ U2c, const void* __restrict__ g2bc,
    const void* __restrict__ Wf1, const void* __restrict__ fb1, const void* __restrict__ fp1,
    const void* __restrict__ Wf2, const void* __restrict__ fb2, const void* __restrict__ fp2,
    const void* __restrict__ Wf3, const void* __restrict__ fb3,
    void* __restrict__ outp)
{
  auto LF=[&](const void* p, size_t i)->float {
    return F32 ? ((const float*)p)[i] : bf2f(((const u16*)p)[i]);
  };
  auto LB=[&](const void* p, size_t i)->u16 {
    return F32 ? f2bf(((const float*)p)[i]) : ((const u16*)p)[i];
  };
  auto FR8=[&](const void* p, size_t off)->s16x8 {
    s16x8 f;
    if (F32){
      const float* pp=(const float*)p+off;
      f32x4 a=*(const f32x4*)pp, b=*(const f32x4*)(pp+4);
#pragma unroll
      for (int j=0;j<4;j++){ f[j]=(short)f2bf(a[j]); f[j+4]=(short)f2bf(b[j]); }
    } else {
      f=*(const s16x8*)((const u16*)p+off);
    }
    return f;
  };

  __shared__ float h1buf[16][68];
  __shared__ float h2buf[16][68];
  __shared__ float pbuf [16][68];
  __shared__ u16   d1buf[16][104];
  __shared__ u16   scL  [16][200];
  __shared__ float hsL  [16][64];
  __shared__ s16x8 u2gL [16][64];
  __shared__ s16x8 u2cL [ 8][64];
  __shared__ float h2o  [16][40];
  __shared__ u16   ueL  [16][64];
  __shared__ u16   ieL  [16][64];
  __shared__ int   lenL [16];

  const int lane=threadIdx.x, q=lane>>4, mm=lane&15;
  const int g=blockIdx.x, b0=g*16;
  const int pb_m=b0+mm;

  {
    int cnt=0;
    for (int t=q*50;t<q*50+50;t++) cnt += (LF(mask,(size_t)pb_m*TT+t)!=0.0f);
    cnt += __shfl_xor(cnt,16);
    cnt += __shfl_xor(cnt,32);
    if (lane<16) lenL[lane]=cnt;
  }
  __syncthreads();
  int lenq[4];
#pragma unroll
  for (int r=0;r<4;r++) lenq[r]=lenL[q*4+r];
  int maxlen=1;
  for (int i=0;i<16;i++) maxlen = (lenL[i]>maxlen)?lenL[i]:maxlen;

  s16x8 wgt[8][4];
#pragma unroll
  for (int nt=0;nt<8;nt++)
#pragma unroll
    for (int c=0;c<4;c++){
      s16x8 f;
#pragma unroll
      for (int j=0;j<8;j++){
        int k=32*c+q*8+j, n=16*nt+mm;
        f[j]=(short)((k<64)?LB(W1g,(size_t)k*128+n):LB(U1g,(size_t)(k-64)*128+n));
      }
      wgt[nt][c]=f;
    }
  s16x8 wct[4][4];
#pragma unroll
  for (int nt=0;nt<4;nt++)
#pragma unroll
    for (int c=0;c<4;c++){
      s16x8 f;
#pragma unroll
      for (int j=0;j<8;j++){
        int k=32*c+q*8+j, n=16*nt+mm;
        f[j]=(short)((k<64)?LB(W1c,(size_t)k*64+n):LB(U1c,(size_t)(k-64)*64+n));
      }
      wct[nt][c]=f;
    }
  float b1gv[8], b1cv[4];
#pragma unroll
  for (int nt=0;nt<8;nt++) b1gv[nt]=LF(g1bg,16*nt+mm);
#pragma unroll
  for (int nt=0;nt<4;nt++) b1cv[nt]=LF(g1bc,16*nt+mm);

  s16x8 w1k[5][2], wd[5][2];
#pragma unroll
  for (int nt=0;nt<5;nt++)
#pragma unroll
    for (int c=0;c<2;c++){
      s16x8 f1,f2;
#pragma unroll
      for (int j=0;j<8;j++){
        int k=32*c+q*8+j, n=16*nt+mm;
        f1[j]=(short)f2bf(LF(Wa1,(size_t)(64+k)*80+n) - LF(Wa1,(size_t)(128+k)*80+n));
        f2[j]=(short)LB(Wa1,(size_t)(192+k)*80+n);
      }
      w1k[nt][c]=f1; wd[nt][c]=f2;
    }
  s16x8 w2f[3][3];
#pragma unroll
  for (int nt=0;nt<3;nt++)
#pragma unroll
    for (int c=0;c<3;c++){
      s16x8 f;
#pragma unroll
      for (int j=0;j<8;j++){
        int k=32*c+q*8+j, n=16*nt+mm;
        f[j]=(short)((k<80 && n<40)?LB(Wa2,(size_t)k*40+n):0);
      }
      w2f[nt][c]=f;
    }
  float ba2v[3], w3v[3];
#pragma unroll
  for (int nt=0;nt<3;nt++){ int n=16*nt+mm; ba2v[nt]=(n<40)?LF(ba2,n):0.0f; w3v[nt]=(n<40)?LF(Wa3,n):0.0f; }
  const float ba3v=LF(ba3,0);

  const int ib=iidx[pb_m];
  const s16x8 qf0=FR8(emb,(size_t)ib*64+q*8);
  const s16x8 qf1=FR8(emb,(size_t)ib*64+32+q*8);

  f32x4 pre[5];
#pragma unroll
  for (int nt=0;nt<5;nt++){
    f32x4 a={0.0f,0.0f,0.0f,0.0f};
#pragma unroll
    for (int c=0;c<2;c++){
      s16x8 f;
#pragma unroll
      for (int j=0;j<8;j++){
        int k=32*c+q*8+j, n=16*nt+mm;
        f[j]=(short)f2bf(LF(Wa1,(size_t)k*80+n) + LF(Wa1,(size_t)(128+k)*80+n));
      }
      a=MFMA16((c==0)?qf0:qf1, f, a);
    }
    float bb=LF(ba1,16*nt+mm);
#pragma unroll
    for (int r=0;r<4;r++) a[r]+=bb;
    pre[nt]=a;
  }

  for (int ii=lane; ii<16*68; ii+=64){ (&h1buf[0][0])[ii]=0.0f; (&h2buf[0][0])[ii]=0.0f; }
  for (int ii=lane; ii<16*104; ii+=64) (&d1buf[0][0])[ii]=0;
  __syncthreads();

  auto load_x=[&](int t, s16x8 &a0, s16x8 &a1){
    int idx = hist[(size_t)pb_m*TT+t];
    a0 = FR8(emb,(size_t)idx*64+q*8);
    a1 = FR8(emb,(size_t)idx*64+32+q*8);
  };

  float hsA[8], hsB[8];
#pragma unroll
  for (int j=0;j<8;j++){ hsA[j]=0.0f; hsB[j]=0.0f; }

  s16x8 xf0,xf1;
  load_x(0,xf0,xf1);
  for (int t=0;t<maxlen;t++){
    s16x8 nx0,nx1;
    { int tn=(t+1<maxlen)?(t+1):(maxlen-1); load_x(tn,nx0,nx1); }

#pragma unroll
    for (int j=0;j<8;j++){ hsA[j]+=bf2f((u16)xf0[j]); hsB[j]+=bf2f((u16)xf1[j]); }

    f32x4 hA0=*(const f32x4*)&h1buf[mm][q*8];
    f32x4 hA1=*(const f32x4*)&h1buf[mm][q*8+4];
    f32x4 hB0=*(const f32x4*)&h1buf[mm][32+q*8];
    f32x4 hB1=*(const f32x4*)&h1buf[mm][32+q*8+4];
    s16x8 hhi0,hlo0,hhi1,hlo1;
    split8(hA0,hA1,hhi0,hlo0);
    split8(hB0,hB1,hhi1,hlo1);

    f32x4 ga[8];
#pragma unroll
    for (int nt=0;nt<8;nt++){
      f32x4 a={0.0f,0.0f,0.0f,0.0f};
      a=MFMA16(xf0 ,wgt[nt][0],a);
      a=MFMA16(xf1 ,wgt[nt][1],a);
      a=MFMA16(hhi0,wgt[nt][2],a);
      a=MFMA16(hhi1,wgt[nt][3],a);
      a=MFMA16(hlo0,wgt[nt][2],a);
      a=MFMA16(hlo1,wgt[nt][3],a);
      ga[nt]=a;
    }
    float zs[4][4], hv[4][4];
#pragma unroll
    for (int nt=0;nt<4;nt++)
#pragma unroll
      for (int r=0;r<4;r++){
        float rg=sigm(ga[nt][r]+b1gv[nt]);
        float h_=h1buf[q*4+r][16*nt+mm];
        hv[nt][r]=h_;
        pbuf[q*4+r][16*nt+mm]=rg*h_;
        zs[nt][r]=sigm(ga[nt+4][r]+b1gv[nt+4]);
      }
    __syncthreads();

    f32x4 pA0=*(const f32x4*)&pbuf[mm][q*8];
    f32x4 pA1=*(const f32x4*)&pbuf[mm][q*8+4];
    f32x4 pB0=*(const f32x4*)&pbuf[mm][32+q*8];
    f32x4 pB1=*(const f32x4*)&pbuf[mm][32+q*8+4];
    s16x8 phi0,plo0,phi1,plo1;
    split8(pA0,pA1,phi0,plo0);
    split8(pB0,pB1,phi1,plo1);

    f32x4 ca[4];
#pragma unroll
    for (int nt=0;nt<4;nt++){
      f32x4 a={0.0f,0.0f,0.0f,0.0f};
      a=MFMA16(xf0 ,wct[nt][0],a);
      a=MFMA16(xf1 ,wct[nt][1],a);
      a=MFMA16(phi0,wct[nt][2],a);
      a=MFMA16(phi1,wct[nt][3],a);
      a=MFMA16(plo0,wct[nt][2],a);
      a=MFMA16(plo1,wct[nt][3],a);
      ca[nt]=a;
    }
#pragma unroll
    for (int nt=0;nt<4;nt++)
#pragma unroll
      for (int r=0;r<4;r++){
        float c=tanh_(ca[nt][r]+b1cv[nt]);
        float z=zs[nt][r];
        float hn=z*hv[nt][r]+(1.0f-z)*c;
        if (t>=lenq[r]) hn=hv[nt][r];
        h1buf[q*4+r][16*nt+mm]=hn;
      }
    __syncthreads();

    f32x4 k0a=*(const f32x4*)&h1buf[mm][q*8];
    f32x4 k0b=*(const f32x4*)&h1buf[mm][q*8+4];
    f32x4 k1a=*(const f32x4*)&h1buf[mm][32+q*8];
    f32x4 k1b=*(const f32x4*)&h1buf[mm][32+q*8+4];
    s16x8 kf0,kf1,kq0,kq1;
#pragma unroll
    for (int j=0;j<4;j++){
      kf0[j]  =(short)f2bf(k0a[j]);  kf0[j+4]=(short)f2bf(k0b[j]);
      kf1[j]  =(short)f2bf(k1a[j]);  kf1[j+4]=(short)f2bf(k1b[j]);
      kq0[j]  =(short)f2bf(k0a[j]*bf2f((u16)qf0[j]));
      kq0[j+4]=(short)f2bf(k0b[j]*bf2f((u16)qf0[j+4]));
      kq1[j]  =(short)f2bf(k1a[j]*bf2f((u16)qf1[j]));
      kq1[j+4]=(short)f2bf(k1b[j]*bf2f((u16)qf1[j+4]));
    }
    f32x4 acc[5];
#pragma unroll
    for (int nt=0;nt<5;nt++){
      f32x4 a=pre[nt];
      a=MFMA16(kf0,w1k[nt][0],a); a=MFMA16(kf1,w1k[nt][1],a);
      a=MFMA16(kq0,wd[nt][0],a);  a=MFMA16(kq1,wd[nt][1],a);
      acc[nt]=a;
    }
#pragma unroll
    for (int nt=0;nt<5;nt++)
#pragma unroll
      for (int r=0;r<4;r++)
        d1buf[q*4+r][16*nt+mm]=f2bf(sigm(acc[nt][r]));
    __syncthreads();
    s16x8 a0=*(const s16x8*)&d1buf[mm][q*8];
    s16x8 a1=*(const s16x8*)&d1buf[mm][32+q*8];
    s16x8 a2=*(const s16x8*)&d1buf[mm][64+q*8];
    f32x4 acc2[3];
#pragma unroll
    for (int nt=0;nt<3;nt++){
      f32x4 a={0.0f,0.0f,0.0f,0.0f};
      a=MFMA16(a0,w2f[nt][0],a); a=MFMA16(a1,w2f[nt][1],a); a=MFMA16(a2,w2f[nt][2],a);
      acc2[nt]=a;
    }
    float part[4];
#pragma unroll
    for (int r=0;r<4;r++){
      float sacc=0.0f;
#pragma unroll
      for (int nt=0;nt<3;nt++) sacc+=sigm(acc2[nt][r]+ba2v[nt])*w3v[nt];
      part[r]=sacc;
    }
#pragma unroll
    for (int d=1;d<16;d<<=1)
#pragma unroll
      for (int r=0;r<4;r++) part[r]+=__shfl_xor(part[r],d);
    if (mm==0){
#pragma unroll
      for (int r=0;r<4;r++) scL[q*4+r][t]=f2bf(part[r]+ba3v);
    }
    __syncthreads();

    xf0=nx0; xf1=nx1;
  }

  for (int t=maxlen;t<TT;t++){
    s16x8 a0,a1; load_x(t,a0,a1);
#pragma unroll
    for (int j=0;j<8;j++){ hsA[j]+=bf2f((u16)a0[j]); hsB[j]+=bf2f((u16)a1[j]); }
  }
#pragma unroll
  for (int j=0;j<8;j++){ hsL[mm][q*8+j]=hsA[j]; hsL[mm][32+q*8+j]=hsB[j]; }
  __syncthreads();

  {
    int row=lane>>2, sub=lane&3;
    int L=lenL[row];
    float mx=-3e38f;
    for (int t=sub;t<L;t+=4) mx=fmaxf(mx,bf2f(scL[row][t]));
    mx=fmaxf(mx,__shfl_xor(mx,1)); mx=fmaxf(mx,__shfl_xor(mx,2));
    float sm=0.0f;
    for (int t=sub;t<L;t+=4) sm+=__expf(bf2f(scL[row][t])-mx);
    sm+=__shfl_xor(sm,1); sm+=__shfl_xor(sm,2);
    float inv=1.0f/sm;
    for (int t=sub;t<TT;t+=4){
      float v=(t<L)?(__expf(bf2f(scL[row][t])-mx)*inv):0.0f;
      scL[row][t]=f2bf(v);
    }
  }
  __syncthreads();

  s16x8 wg2x[8][2], wc2x[4][2];
#pragma unroll
  for (int nt=0;nt<8;nt++)
#pragma unroll
    for (int c=0;c<2;c++){
      s16x8 f,fh;
#pragma unroll
      for (int j=0;j<8;j++){
        int k=32*c+q*8+j, n=16*nt+mm;
        f[j] =(short)LB(W2g,(size_t)k*128+n);
        fh[j]=(short)LB(U2g,(size_t)k*128+n);
      }
      wg2x[nt][c]=f;
      u2gL[nt*2+c][lane]=fh;
    }
#pragma unroll
  for (int nt=0;nt<4;nt++)
#pragma unroll
    for (int c=0;c<2;c++){
      s16x8 f,fh;
#pragma unroll
      for (int j=0;j<8;j++){
        int k=32*c+q*8+j, n=16*nt+mm;
        f[j] =(short)LB(W2c,(size_t)k*64+n);
        fh[j]=(short)LB(U2c,(size_t)k*64+n);
      }
      wc2x[nt][c]=f;
      u2cL[nt*2+c][lane]=fh;
    }
  float b2gv[8], b2cv[4];
#pragma unroll
  for (int nt=0;nt<8;nt++) b2gv[nt]=LF(g2bg,16*nt+mm);
#pragma unroll
  for (int nt=0;nt<4;nt++) b2cv[nt]=LF(g2bc,16*nt+mm);

  for (int ii=lane; ii<16*68; ii+=64){ (&h1buf[0][0])[ii]=0.0f; (&h2buf[0][0])[ii]=0.0f; }
  __syncthreads();

  load_x(0,xf0,xf1);
  for (int t=0;t<maxlen;t++){
    s16x8 nx0,nx1;
    { int tn=(t+1<maxlen)?(t+1):(maxlen-1); load_x(tn,nx0,nx1); }

    {
      f32x4 hA0=*(const f32x4*)&h1buf[mm][q*8];
      f32x4 hA1=*(const f32x4*)&h1buf[mm][q*8+4];
      f32x4 hB0=*(const f32x4*)&h1buf[mm][32+q*8];
      f32x4 hB1=*(const f32x4*)&h1buf[mm][32+q*8+4];
      s16x8 hhi0,hlo0,hhi1,hlo1;
      split8(hA0,hA1,hhi0,hlo0);
      split8(hB0,hB1,hhi1,hlo1);
      f32x4 ga[8];
#pragma unroll
      for (int nt=0;nt<8;nt++){
        f32x4 a={0.0f,0.0f,0.0f,0.0f};
        a=MFMA16(xf0 ,wgt[nt][0],a);
        a=MFMA16(xf1 ,wgt[nt][1],a);
        a=MFMA16(hhi0,wgt[nt][2],a);
        a=MFMA16(hhi1,wgt[nt][3],a);
        a=MFMA16(hlo0,wgt[nt][2],a);
        a=MFMA16(hlo1,wgt[nt][3],a);
        ga[nt]=a;
      }
      float zs[4][4], hv[4][4];
#pragma unroll
      for (int nt=0;nt<4;nt++)
#pragma unroll
        for (int r=0;r<4;r++){
          float rg=sigm(ga[nt][r]+b1gv[nt]);
          float h_=h1buf[q*4+r][16*nt+mm];
          hv[nt][r]=h_;
          pbuf[q*4+r][16*nt+mm]=rg*h_;
          zs[nt][r]=sigm(ga[nt+4][r]+b1gv[nt+4]);
        }
      __syncthreads();
      f32x4 pA0=*(const f32x4*)&pbuf[mm][q*8];
      f32x4 pA1=*(const f32x4*)&pbuf[mm][q*8+4];
      f32x4 pB0=*(const f32x4*)&pbuf[mm][32+q*8];
      f32x4 pB1=*(const f32x4*)&pbuf[mm][32+q*8+4];
      s16x8 phi0,plo0,phi1,plo1;
      split8(pA0,pA1,phi0,plo0);
      split8(pB0,pB1,phi1,plo1);
      f32x4 ca[4];
#pragma unroll
      for (int nt=0;nt<4;nt++){
        f32x4 a={0.0f,0.0f,0.0f,0.0f};
        a=MFMA16(xf0 ,wct[nt][0],a);
        a=MFMA16(xf1 ,wct[nt][1],a);
        a=MFMA16(phi0,wct[nt][2],a);
        a=MFMA16(phi1,wct[nt][3],a);
        a=MFMA16(plo0,wct[nt][2],a);
        a=MFMA16(plo1,wct[nt][3],a);
        ca[nt]=a;
      }
#pragma unroll
      for (int nt=0;nt<4;nt++)
#pragma unroll
        for (int r=0;r<4;r++){
          float c=tanh_(ca[nt][r]+b1cv[nt]);
          float z=zs[nt][r];
          float hn=z*hv[nt][r]+(1.0f-z)*c;
          if (t>=lenq[r]) hn=hv[nt][r];
          h1buf[q*4+r][16*nt+mm]=hn;
        }
      __syncthreads();
    }

    {
      float al=bf2f(scL[mm][t]);
      f32x4 x0a=*(const f32x4*)&h1buf[mm][q*8];
      f32x4 x0b=*(const f32x4*)&h1buf[mm][q*8+4];
      f32x4 x1a=*(const f32x4*)&h1buf[mm][32+q*8];
      f32x4 x1b=*(const f32x4*)&h1buf[mm][32+q*8+4];
      s16x8 af0,af1;
#pragma unroll
      for (int j=0;j<4;j++){
        af0[j]  =(short)f2bf(x0a[j]*al); af0[j+4]=(short)f2bf(x0b[j]*al);
        af1[j]  =(short)f2bf(x1a[j]*al); af1[j+4]=(short)f2bf(x1b[j]*al);
      }
      f32x4 hA0=*(const f32x4*)&h2buf[mm][q*8];
      f32x4 hA1=*(const f32x4*)&h2buf[mm][q*8+4];
      f32x4 hB0=*(const f32x4*)&h2buf[mm][32+q*8];
      f32x4 hB1=*(const f32x4*)&h2buf[mm][32+q*8+4];
      s16x8 hhi0,hlo0,hhi1,hlo1;
      split8(hA0,hA1,hhi0,hlo0);
      split8(hB0,hB1,hhi1,hlo1);
      f32x4 ga[8];
#pragma unroll
      for (int nt=0;nt<8;nt++){
        s16x8 wh0=u2gL[nt*2+0][lane];
        s16x8 wh1=u2gL[nt*2+1][lane];
        f32x4 a={0.0f,0.0f,0.0f,0.0f};
        a=MFMA16(af0 ,wg2x[nt][0],a);
        a=MFMA16(af1 ,wg2x[nt][1],a);
        a=MFMA16(hhi0,wh0,a);
        a=MFMA16(hhi1,wh1,a);
        a=MFMA16(hlo0,wh0,a);
        a=MFMA16(hlo1,wh1,a);
        ga[nt]=a;
      }
      float zs[4][4], hv[4][4];
#pragma unroll
      for (int nt=0;nt<4;nt++)
#pragma unroll
        for (int r=0;r<4;r++){
          float rg=sigm(ga[nt][r]+b2gv[nt]);
          float h_=h2buf[q*4+r][16*nt+mm];
          hv[nt][r]=h_;
          pbuf[q*4+r][16*nt+mm]=rg*h_;
          zs[nt][r]=sigm(ga[nt+4][r]+b2gv[nt+4]);
        }
      __syncthreads();
      f32x4 pA0=*(const f32x4*)&pbuf[mm][q*8];
      f32x4 pA1=*(const f32x4*)&pbuf[mm][q*8+4];
      f32x4 pB0=*(const f32x4*)&pbuf[mm][32+q*8];
      f32x4 pB1=*(const f32x4*)&pbuf[mm][32+q*8+4];
      s16x8 phi0,plo0,phi1,plo1;
      split8(pA0,pA1,phi0,plo0);
      split8(pB0,pB1,phi1,plo1);
      f32x4 ca[4];
#pragma unroll
      for (int nt=0;nt<4;nt++){
        s16x8 wh0=u2cL[nt*2+0][lane];
        s16x8 wh1=u2cL[nt*2+1][lane];
        f32x4 a={0.0f,0.0f,0.0f,0.0f};
        a=MFMA16(af0 ,wc2x[nt][0],a);
        a=MFMA16(af1 ,wc2x[nt][1],a);
        a=MFMA16(phi0,wh0,a);
        a=MFMA16(phi1,wh1,a);
        a=MFMA16(plo0,wh0,a);
        a=MFMA16(plo1,wh1,a);
        ca[nt]=a;
      }
#pragma unroll
      for (int nt=0;nt<4;nt++)
#pragma unroll
        for (int r=0;r<4;r++){
          float c=tanh_(ca[nt][r]+b2cv[nt]);
          float z=zs[nt][r];
          float hn=z*hv[nt][r]+(1.0f-z)*c;
          if (t>=lenq[r]) hn=hv[nt][r];
          h2buf[q*4+r][16*nt+mm]=hn;
        }
      __syncthreads();
    }

    xf0=nx0; xf1=nx1;
  }

  {
    int row=lane>>2, c0=(lane&3)*16;
    int ub=uidx[b0+row], ibv=iidx[b0+row];
#pragma unroll
    for (int j=0;j<16;j++){
      ueL[row][c0+j]=LB(uemb,(size_t)ub*64+c0+j);
      ieL[row][c0+j]=LB(emb ,(size_t)ibv*64+c0+j);
    }
  }
  __syncthreads();

  {
    f32x4 acc1[8];
#pragma unroll
    for (int nt=0;nt<8;nt++) acc1[nt]=f32x4{0.0f,0.0f,0.0f,0.0f};
#pragma unroll
    for (int kc=0;kc<10;kc++){
      const int seg=kc>>1, off=(kc&1)*32+q*8;
      s16x8 af;
#pragma unroll
      for (int j=0;j<8;j++){
        int f=off+j;
        u16 v;
        if      (seg==0) v=ueL[mm][f];
        else if (seg==1) v=ieL[mm][f];
        else if (seg==2) v=f2bf(hsL[mm][f]);
        else if (seg==3) v=f2bf(bf2f(ieL[mm][f])*hsL[mm][f]);
        else             v=f2bf(h2buf[mm][f]);
        af[j]=(short)v;
      }
#pragma unroll
      for (int nt=0;nt<8;nt++){
        s16x8 bfr;
#pragma unroll
        for (int j=0;j<8;j++) bfr[j]=(short)LB(Wf1,(size_t)(32*kc+q*8+j)*128 + 16*nt+mm);
        acc1[nt]=MFMA16(af,bfr,acc1[nt]);
      }
    }
    __syncthreads();
#pragma unroll
    for (int nt=0;nt<8;nt++)
#pragma unroll
      for (int r=0;r<4;r++){
        int col=16*nt+mm, row=q*4+r;
        float x=acc1[nt][r]+LF(fb1,col);
        float pp=LF(fp1,col);
        scL[row][col]=f2bf((x>=0.0f)?x:pp*x);
      }
  }
  __syncthreads();

  {
    f32x4 acc2[3];
#pragma unroll
    for (int nt=0;nt<3;nt++) acc2[nt]=f32x4{0.0f,0.0f,0.0f,0.0f};
#pragma unroll
    for (int kc=0;kc<4;kc++){
      s16x8 af=*(const s16x8*)&scL[mm][32*kc+q*8];
#pragma unroll
      for (int nt=0;nt<3;nt++){
        s16x8 bfr;
#pragma unroll
        for (int j=0;j<8;j++){
          int k=32*kc+q*8+j, n=16*nt+mm;
          bfr[j]=(short)((n<40)?LB(Wf2,(size_t)k*40+n):0);
        }
        acc2[nt]=MFMA16(af,bfr,acc2[nt]);
      }
    }
#pragma unroll
    for (int nt=0;nt<3;nt++)
#pragma unroll
      for (int r=0;r<4;r++){
        int col=16*nt+mm, row=q*4+r;
        if (col<40){
          float x=acc2[nt][r]+LF(fb2,col);
          float pp=LF(fp2,col);
          h2o[row][col]=(x>=0.0f)?x:pp*x;
        }
      }
  }
  __syncthreads();

  {
    int row=lane>>2, sub=lane&3;
    float s=0.0f;
    for (int k=sub;k<40;k+=4) s+=h2o[row][k]*LF(Wf3,k);
    s+=__shfl_xor(s,1); s+=__shfl_xor(s,2);
    if (sub==0){
      float v=s+LF(fb3,0);
      if (F32) ((float*)outp)[b0+row]=v;
      else     ((u16*) outp)[b0+row]=f2bf(v);
    }
  }
}

extern "C" void kernel_launch(void* const* d_in, const int* in_sizes, int n_in,
                              void* d_out, int out_size, void* d_ws, size_t ws_size,
                              hipStream_t stream)
{
  (void)in_sizes; (void)n_in; (void)out_size;
  const int* u    =(const int*)d_in[0];
  const int* it   =(const int*)d_in[1];
  const int* hist =(const int*)d_in[2];
  const float* mask=(const float*)d_in[3];
  const float* item_emb=(const float*)d_in[4];
  const float* user_emb=(const float*)d_in[5];
  const float* g1Wg=(const float*)d_in[6],  *g1Ug=(const float*)d_in[7],  *g1bg=(const float*)d_in[8];
  const float* g1Wc=(const float*)d_in[9],  *g1Uc=(const float*)d_in[10], *g1bc=(const float*)d_in[11];
  const float* Wa1=(const float*)d_in[12], *ba1=(const float*)d_in[13];
  const float* Wa2=(const float*)d_in[14], *ba2=(const float*)d_in[15];
  const float* Wa3=(const float*)d_in[16], *ba3=(const float*)d_in[17];
  const float* g2Wg=(const float*)d_in[18], *g2Ug=(const float*)d_in[19], *g2bg=(const float*)d_in[20];
  const float* g2Wc=(const float*)d_in[21], *g2Uc=(const float*)d_in[22], *g2bc=(const float*)d_in[23];
  const float* W1=(const float*)d_in[24], *b1=(const float*)d_in[25], *p1=(const float*)d_in[26];
  const float* W2=(const float*)d_in[27], *b2=(const float*)d_in[28], *p2=(const float*)d_in[29];
  const float* W3=(const float*)d_in[30], *b3=(const float*)d_in[31];

  const size_t sz_rnn1  =(size_t)BB*TT*64*2;
  const size_t sz_scores=(size_t)BB*TT*4;
  const size_t sz_len   =(size_t)BB*4;
  const size_t sz_hs    =(size_t)BB*64*4;
  const size_t sz_f2    =(size_t)BB*64*4;
  const size_t NEED = sz_rnn1+sz_scores+sz_len+sz_hs+sz_f2 + 1024;

  if (ws_size >= NEED){
    char* ws=(char*)d_ws;
    u16*   rnn1  =(u16*)  ws;                    ws+=sz_rnn1;
    float* alpha =(float*)ws;                    ws+=sz_scores;
    int*   len_g =(int*)  ws;                    ws+=sz_len;
    float* hs    =(float*)ws;                    ws+=sz_hs;
    float* f2    =(float*)ws;

    hist_sum_kernel<<<BB*8/256,256,0,stream>>>(hist, item_emb, hs);
    scan1_kernel<<<BB/8,  256, 0, stream>>>(hist, mask, item_emb,
                                            g1Wg,g1Ug,g1bg,g1Wc,g1Uc,g1bc,
                                            len_g, rnn1);
    attn_kernel <<<BB,     64, 0, stream>>>(it, item_emb, rnn1,
                                            Wa1,ba1,Wa2,ba2,Wa3,ba3,
                                            len_g, alpha);
    scan2_kernel<<<BB/8,  256, 0, stream>>>(rnn1, alpha, len_g,
                                            g2Wg,g2Ug,g2bg,g2Wc,g2Uc,g2bc,
                                            f2);
    fcn_kernel  <<<BB/16,  64, 0, stream>>>(u, it, user_emb, item_emb, hs, f2,
                                            W1,b1,p1,W2,b2,p2,W3,b3,
                                            (float*)d_out);
  } else {
    dien_mega_kernel<true><<<BB/16, 64, 0, stream>>>(
        u, it, hist, mask, item_emb, user_emb,
        g1Wg,g1Ug,g1bg,g1Wc,g1Uc,g1bc,
        Wa1,ba1,Wa2,ba2,Wa3,ba3,
        g2Wg,g2Ug,g2bg,g2Wc,g2Uc,g2bc,
        W1,b1,p1,W2,b2,p2,W3,b3,
        d_out);
  }
}

// Round 8
// 895.631 us; speedup vs baseline: 1.3123x; 1.3123x over previous
//
#include <hip/hip_runtime.h>

#define BB 4096
#define TT 200
// E = H = 64

typedef unsigned short u16;
typedef unsigned int   u32;
typedef unsigned short u16x8 __attribute__((ext_vector_type(8)));
typedef short s16x8 __attribute__((ext_vector_type(8)));
typedef float f32x4 __attribute__((ext_vector_type(4)));

__device__ __forceinline__ float bf2f(u16 u){ union{unsigned u; float f;} v; v.u=((unsigned)u)<<16; return v.f; }
__device__ __forceinline__ u16 f2bf(float f){ union{float f; unsigned u;} v; v.f=f; unsigned r=v.u + 0x7FFFu + ((v.u>>16)&1u); return (u16)(r>>16); }
__device__ __forceinline__ float sigm(float x){ return 1.0f/(1.0f+__expf(-x)); }
__device__ __forceinline__ float tanh_(float x){ return 1.0f - 2.0f/(1.0f+__expf(2.0f*x)); }

#define MFMA16(a,b,c) __builtin_amdgcn_mfma_f32_16x16x32_bf16((a),(b),(c),0,0,0)

// scalar split (fallback/mega path only). R6 measured v_cvt_pk_bf16_f32 slower — keep scalar.
__device__ __forceinline__ void split8(const f32x4 a, const f32x4 b, s16x8 &hi, s16x8 &lo){
#pragma unroll
  for (int j=0;j<4;j++){
    float v=a[j]; u16 h=(u16)(__float_as_uint(v)>>16);
    hi[j]=(short)h; lo[j]=(short)f2bf(v-bf2f(h));
    v=b[j]; h=(u16)(__float_as_uint(v)>>16);
    hi[j+4]=(short)h; lo[j+4]=(short)f2bf(v-bf2f(h));
  }
}

// ================================================================
// FAST PATH: conv(emb->bf16) -> hist_sum -> scan1 -> attn(+softmax,+attin) -> scan2 -> fcn
// Scans: 16 rows/block, 4-wave N-split, h in registers, producer-side hi/lo LDS packing.
// ================================================================

// ---------------- item_emb fp32 -> bf16 table ----------------
__global__ void conv_kernel(const float* __restrict__ src, u16* __restrict__ dst, int n){
  int i=(blockIdx.x*256+threadIdx.x)*8;
  if (i>=n) return;
  f32x4 a=*(const f32x4*)(src+i), b=*(const f32x4*)(src+i+4);
  u16x8 o;
#pragma unroll
  for (int j=0;j<4;j++){ o[j]=f2bf(a[j]); o[j+4]=f2bf(b[j]); }
  *(u16x8*)(dst+i)=o;
}

// ---------------- hist_sum (unmasked, parallel; reads bf16 table) ----------------
__global__ void hist_sum_kernel(const int* __restrict__ hist, const u16* __restrict__ emb16,
                                float* __restrict__ hs){
  int tid = blockIdx.x*256 + threadIdx.x;     // B*8 threads
  int b = tid>>3, cg = (tid&7)*8;
  float acc[8];
#pragma unroll
  for (int j=0;j<8;j++) acc[j]=0.0f;
  for (int t=0;t<TT;t++){
    int idx = hist[(size_t)b*TT+t];
    u16x8 v=*(const u16x8*)(emb16+(size_t)idx*64+cg);
#pragma unroll
    for (int j=0;j<8;j++) acc[j]+=bf2f(v[j]);
  }
#pragma unroll
  for (int j=0;j<8;j++) hs[(size_t)b*64+cg+j]=acc[j];
}

// ---------------- scan1: gru1, 16 rows/block, h in regs, hi/lo LDS ----------------
__global__ __launch_bounds__(256,1) void scan1_kernel(
    const int* __restrict__ hist, const float* __restrict__ mask, const u16* __restrict__ emb16,
    const float* __restrict__ Wg, const float* __restrict__ Ug, const float* __restrict__ bg,
    const float* __restrict__ Wc, const float* __restrict__ Uc, const float* __restrict__ bc,
    int* __restrict__ len_g, u16* __restrict__ rnn1)
{
  __shared__ __attribute__((aligned(16))) u16 hhiL[16][72];
  __shared__ __attribute__((aligned(16))) u16 hloL[16][72];
  __shared__ __attribute__((aligned(16))) u16 phiL[16][72];
  __shared__ __attribute__((aligned(16))) u16 ploL[16][72];
  __shared__ int lenL[16];
  const int tid=threadIdx.x;
  const int w=tid>>6, lane=tid&63, q=lane>>4, mm=lane&15;
  const int g=blockIdx.x, b0=g*16, pb_m=b0+mm;

  if (w==0){
    int cnt=0;
    for (int t=q*50;t<q*50+50;t++) cnt += (mask[(size_t)pb_m*TT+t]!=0.0f);
    cnt += __shfl_xor(cnt,16);
    cnt += __shfl_xor(cnt,32);
    if (lane<16){ lenL[lane]=cnt; len_g[b0+lane]=cnt; }
  }
  for (int ii=tid; ii<16*72; ii+=256){ (&hhiL[0][0])[ii]=0; (&hloL[0][0])[ii]=0; }
  __syncthreads();

  int lenq[4];
#pragma unroll
  for (int r=0;r<4;r++) lenq[r]=lenL[q*4+r];
  int maxlen=1;
  for (int i=0;i<16;i++) maxlen=(lenL[i]>maxlen)?lenL[i]:maxlen;

  const int nr=16*w+mm, nz=64+16*w+mm;
  s16x8 wgr[4], wgz[4], wcf[4];
#pragma unroll
  for (int c=0;c<4;c++){
    s16x8 fr,fz,fc;
#pragma unroll
    for (int j=0;j<8;j++){
      int k=32*c+q*8+j;
      fr[j]=(short)f2bf((k<64)?Wg[(size_t)k*128+nr]:Ug[(size_t)(k-64)*128+nr]);
      fz[j]=(short)f2bf((k<64)?Wg[(size_t)k*128+nz]:Ug[(size_t)(k-64)*128+nz]);
      fc[j]=(short)f2bf((k<64)?Wc[(size_t)k*64+nr]:Uc[(size_t)(k-64)*64+nr]);
    }
    wgr[c]=fr; wgz[c]=fz; wcf[c]=fc;
  }
  const float bgr=bg[nr], bgz=bg[nz], bcv=bc[nr];

  float hreg[4]={0.0f,0.0f,0.0f,0.0f};

  auto load_x=[&](int t, s16x8 &a0, s16x8 &a1){
    int idx = hist[(size_t)pb_m*TT+t];
    const u16* p=emb16+(size_t)idx*64;
    a0=*(const s16x8*)(p+q*8);
    a1=*(const s16x8*)(p+32+q*8);
  };

  s16x8 xf0,xf1;
  load_x(0,xf0,xf1);
  for (int t=0;t<maxlen;t++){
    s16x8 nx0,nx1;
    { int tn=(t+1<maxlen)?(t+1):(maxlen-1); load_x(tn,nx0,nx1); }

    s16x8 hhi0=*(const s16x8*)&hhiL[mm][q*8];
    s16x8 hhi1=*(const s16x8*)&hhiL[mm][32+q*8];
    s16x8 hlo0=*(const s16x8*)&hloL[mm][q*8];
    s16x8 hlo1=*(const s16x8*)&hloL[mm][32+q*8];

    f32x4 ar0={0.0f,0.0f,0.0f,0.0f}, ar1={0.0f,0.0f,0.0f,0.0f};
    f32x4 az0={0.0f,0.0f,0.0f,0.0f}, az1={0.0f,0.0f,0.0f,0.0f};
    ar0=MFMA16(xf0 ,wgr[0],ar0); az0=MFMA16(xf0 ,wgz[0],az0);
    ar0=MFMA16(xf1 ,wgr[1],ar0); az0=MFMA16(xf1 ,wgz[1],az0);
    ar0=MFMA16(hhi0,wgr[2],ar0); az0=MFMA16(hhi0,wgz[2],az0);
    ar1=MFMA16(hhi1,wgr[3],ar1); az1=MFMA16(hhi1,wgz[3],az1);
    ar1=MFMA16(hlo0,wgr[2],ar1); az1=MFMA16(hlo0,wgz[2],az1);
    ar1=MFMA16(hlo1,wgr[3],ar1); az1=MFMA16(hlo1,wgz[3],az1);
    f32x4 ar=ar0+ar1, az=az0+az1;

    float zs[4];
#pragma unroll
    for (int r=0;r<4;r++){
      float rg=sigm(ar[r]+bgr);
      float pv=rg*hreg[r];
      u16 ph=(u16)(__float_as_uint(pv)>>16);
      phiL[q*4+r][16*w+mm]=ph;
      ploL[q*4+r][16*w+mm]=f2bf(pv-bf2f(ph));
      zs[r]=sigm(az[r]+bgz);
    }
    __syncthreads();

    s16x8 phi0=*(const s16x8*)&phiL[mm][q*8];
    s16x8 phi1=*(const s16x8*)&phiL[mm][32+q*8];
    s16x8 plo0=*(const s16x8*)&ploL[mm][q*8];
    s16x8 plo1=*(const s16x8*)&ploL[mm][32+q*8];

    f32x4 ac0={0.0f,0.0f,0.0f,0.0f}, ac1={0.0f,0.0f,0.0f,0.0f};
    ac0=MFMA16(xf0 ,wcf[0],ac0);
    ac0=MFMA16(xf1 ,wcf[1],ac0);
    ac0=MFMA16(phi0,wcf[2],ac0);
    ac1=MFMA16(phi1,wcf[3],ac1);
    ac1=MFMA16(plo0,wcf[2],ac1);
    ac1=MFMA16(plo1,wcf[3],ac1);
    f32x4 ac=ac0+ac1;
#pragma unroll
    for (int r=0;r<4;r++){
      float c=tanh_(ac[r]+bcv);
      float hn=zs[r]*hreg[r]+(1.0f-zs[r])*c;
      if (t>=lenq[r]) hn=hreg[r];
      hreg[r]=hn;
      u16 hh=f2bf(hn);              // RNE hi (also the rnn1 value)
      hhiL[q*4+r][16*w+mm]=hh;
      hloL[q*4+r][16*w+mm]=f2bf(hn-bf2f(hh));
      rnn1[((size_t)(b0+q*4+r)*TT+t)*64 + 16*w+mm]=hh;
    }
    __syncthreads();
    xf0=nx0; xf1=nx1;
  }
}

// ---------------- attn + fused softmax + attin=rnn1*alpha: 1 wave/row ----------------
__global__ __launch_bounds__(64,1) void attn_kernel(
    const int* __restrict__ iidx, const float* __restrict__ emb, const u16* __restrict__ rnn1,
    const float* __restrict__ Wa1, const float* __restrict__ ba1,
    const float* __restrict__ Wa2, const float* __restrict__ ba2,
    const float* __restrict__ Wa3, const float* __restrict__ ba3,
    const int* __restrict__ len_g, u16* __restrict__ attin)
{
  __shared__ __attribute__((aligned(16))) u16 d1buf[16][104];
  __shared__ float scS[208];
  const int lane=threadIdx.x, q=lane>>4, mm=lane&15;
  const int b=blockIdx.x;
  const int L=len_g[b];

  s16x8 w1k[5][2], wd[5][2];
#pragma unroll
  for (int nt=0;nt<5;nt++)
#pragma unroll
    for (int c=0;c<2;c++){
      s16x8 f1,f2;
#pragma unroll
      for (int j=0;j<8;j++){
        int k=32*c+q*8+j, n=16*nt+mm;
        f1[j]=(short)f2bf(Wa1[(size_t)(64+k)*80+n] - Wa1[(size_t)(128+k)*80+n]);
        f2[j]=(short)f2bf(Wa1[(size_t)(192+k)*80+n]);
      }
      w1k[nt][c]=f1; wd[nt][c]=f2;
    }
  s16x8 w2f[3][3];
#pragma unroll
  for (int nt=0;nt<3;nt++)
#pragma unroll
    for (int c=0;c<3;c++){
      s16x8 f;
#pragma unroll
      for (int j=0;j<8;j++){
        int k=32*c+q*8+j, n=16*nt+mm;
        f[j]=(short)((k<80 && n<40)?f2bf(Wa2[(size_t)k*40+n]):0);
      }
      w2f[nt][c]=f;
    }
  float ba2v[3], w3v[3];
#pragma unroll
  for (int nt=0;nt<3;nt++){ int n=16*nt+mm; ba2v[nt]=(n<40)?ba2[n]:0.0f; w3v[nt]=(n<40)?Wa3[n]:0.0f; }
  const float ba3v=ba3[0];

  const int ib=iidx[b];
  float qv0[8], qv1[8];
  s16x8 aq0,aq1;
#pragma unroll
  for (int j=0;j<8;j++){
    qv0[j]=emb[(size_t)ib*64+q*8+j];
    qv1[j]=emb[(size_t)ib*64+32+q*8+j];
    aq0[j]=(short)f2bf(qv0[j]); aq1[j]=(short)f2bf(qv1[j]);
  }
  float pre[5];
#pragma unroll
  for (int nt=0;nt<5;nt++){
    int n=16*nt+mm;
    s16x8 bp0,bp1;
#pragma unroll
    for (int j=0;j<8;j++){
      int k=q*8+j, k2=32+q*8+j;
      bp0[j]=(short)f2bf(Wa1[(size_t)k *80+n]+Wa1[(size_t)(128+k )*80+n]);
      bp1[j]=(short)f2bf(Wa1[(size_t)k2*80+n]+Wa1[(size_t)(128+k2)*80+n]);
    }
    f32x4 a={0.0f,0.0f,0.0f,0.0f};
    a=MFMA16(aq0,bp0,a); a=MFMA16(aq1,bp1,a);
    pre[nt]=a[0]+ba1[n];
  }

  for (int ii=lane; ii<16*104; ii+=64) (&d1buf[0][0])[ii]=0;
  for (int t=lane;t<208;t+=64) scS[t]=-1e9f;
  __syncthreads();

  const int nch=(L+15)>>4;
  for (int ch=0; ch<nch; ch++){
    int t0=ch*16;
    size_t base=((size_t)b*TT + t0+mm)*64;
    s16x8 kf0=*(const s16x8*)(rnn1+base+q*8);
    s16x8 kf1=*(const s16x8*)(rnn1+base+32+q*8);
    s16x8 kq0,kq1;
#pragma unroll
    for (int j=0;j<8;j++){
      kq0[j]=(short)f2bf(bf2f((u16)kf0[j])*qv0[j]);
      kq1[j]=(short)f2bf(bf2f((u16)kf1[j])*qv1[j]);
    }
    f32x4 acc[5];
#pragma unroll
    for (int nt=0;nt<5;nt++){
      f32x4 a={pre[nt],pre[nt],pre[nt],pre[nt]};
      a=MFMA16(kf0,w1k[nt][0],a); a=MFMA16(kf1,w1k[nt][1],a);
      a=MFMA16(kq0,wd[nt][0],a);  a=MFMA16(kq1,wd[nt][1],a);
      acc[nt]=a;
    }
#pragma unroll
    for (int nt=0;nt<5;nt++)
#pragma unroll
      for (int r=0;r<4;r++)
        d1buf[q*4+r][16*nt+mm]=f2bf(sigm(acc[nt][r]));
    __syncthreads();
    s16x8 a0=*(const s16x8*)&d1buf[mm][q*8];
    s16x8 a1=*(const s16x8*)&d1buf[mm][32+q*8];
    s16x8 a2=*(const s16x8*)&d1buf[mm][64+q*8];
    f32x4 acc2[3];
#pragma unroll
    for (int nt=0;nt<3;nt++){
      f32x4 a={0.0f,0.0f,0.0f,0.0f};
      a=MFMA16(a0,w2f[nt][0],a); a=MFMA16(a1,w2f[nt][1],a); a=MFMA16(a2,w2f[nt][2],a);
      acc2[nt]=a;
    }
    float part[4];
#pragma unroll
    for (int r=0;r<4;r++){
      float s=0.0f;
#pragma unroll
      for (int nt=0;nt<3;nt++) s+=sigm(acc2[nt][r]+ba2v[nt])*w3v[nt];
      part[r]=s;
    }
#pragma unroll
    for (int d=1;d<16;d<<=1)
#pragma unroll
      for (int r=0;r<4;r++) part[r]+=__shfl_xor(part[r],d);
    if (mm==0){
#pragma unroll
      for (int r=0;r<4;r++){ int t=t0+q*4+r; scS[t]=(t<L)?(part[r]+ba3v):-1e9f; }
    }
    __syncthreads();
  }

  // masked softmax
  float mx=-3e38f;
  for (int t=lane;t<TT;t+=64) mx=fmaxf(mx,scS[t]);
#pragma unroll
  for (int d=1;d<64;d<<=1) mx=fmaxf(mx,__shfl_xor(mx,d));
  float sm=0.0f;
  for (int t=lane;t<TT;t+=64) sm+=__expf(scS[t]-mx);
#pragma unroll
  for (int d=1;d<64;d<<=1) sm+=__shfl_xor(sm,d);
  float inv=1.0f/sm;

  // attin = rnn1 * alpha (bf16). 8 t's per iteration; alpha=0 past L kills stale rnn1.
  {
    int toff=lane>>3, cg=(lane&7)*8;
    for (int t0=0;t0<TT;t0+=8){
      int tt=t0+toff;
      float al=(tt<L)?(__expf(scS[tt]-mx)*inv):0.0f;
      size_t base=((size_t)b*TT+tt)*64+cg;
      u16x8 kk=*(const u16x8*)(rnn1+base);
      s16x8 o;
#pragma unroll
      for (int j=0;j<8;j++) o[j]=(short)f2bf(bf2f(kk[j])*al);
      *(s16x8*)(attin+base)=o;
    }
  }
}

// ---------------- scan2: gru2, 16 rows/block, x = attin (pure loads) ----------------
__global__ __launch_bounds__(256,1) void scan2_kernel(
    const u16* __restrict__ attin, const int* __restrict__ len_g,
    const float* __restrict__ Wg, const float* __restrict__ Ug, const float* __restrict__ bg,
    const float* __restrict__ Wc, const float* __restrict__ Uc, const float* __restrict__ bc,
    float* __restrict__ f2)
{
  __shared__ __attribute__((aligned(16))) u16 hhiL[16][72];
  __shared__ __attribute__((aligned(16))) u16 hloL[16][72];
  __shared__ __attribute__((aligned(16))) u16 phiL[16][72];
  __shared__ __attribute__((aligned(16))) u16 ploL[16][72];
  __shared__ int lenL[16];
  const int tid=threadIdx.x;
  const int w=tid>>6, lane=tid&63, q=lane>>4, mm=lane&15;
  const int g=blockIdx.x, b0=g*16, pb_m=b0+mm;

  if (tid<16) lenL[tid]=len_g[b0+tid];
  for (int ii=tid; ii<16*72; ii+=256){ (&hhiL[0][0])[ii]=0; (&hloL[0][0])[ii]=0; }
  __syncthreads();

  int lenq[4];
#pragma unroll
  for (int r=0;r<4;r++) lenq[r]=lenL[q*4+r];
  int maxlen=1;
  for (int i=0;i<16;i++) maxlen=(lenL[i]>maxlen)?lenL[i]:maxlen;

  const int nr=16*w+mm, nz=64+16*w+mm;
  s16x8 wgr[4], wgz[4], wcf[4];
#pragma unroll
  for (int c=0;c<4;c++){
    s16x8 fr,fz,fc;
#pragma unroll
    for (int j=0;j<8;j++){
      int k=32*c+q*8+j;
      fr[j]=(short)f2bf((k<64)?Wg[(size_t)k*128+nr]:Ug[(size_t)(k-64)*128+nr]);
      fz[j]=(short)f2bf((k<64)?Wg[(size_t)k*128+nz]:Ug[(size_t)(k-64)*128+nz]);
      fc[j]=(short)f2bf((k<64)?Wc[(size_t)k*64+nr]:Uc[(size_t)(k-64)*64+nr]);
    }
    wgr[c]=fr; wgz[c]=fz; wcf[c]=fc;
  }
  const float bgr=bg[nr], bgz=bg[nz], bcv=bc[nr];

  float hreg[4]={0.0f,0.0f,0.0f,0.0f};

  auto load_x=[&](int t, s16x8 &a0, s16x8 &a1){
    size_t base=((size_t)pb_m*TT+t)*64;
    a0=*(const s16x8*)(attin+base+q*8);
    a1=*(const s16x8*)(attin+base+32+q*8);
  };

  s16x8 xf0,xf1;
  load_x(0,xf0,xf1);
  for (int t=0;t<maxlen;t++){
    s16x8 nx0,nx1;
    { int tn=(t+1<maxlen)?(t+1):(maxlen-1); load_x(tn,nx0,nx1); }

    s16x8 hhi0=*(const s16x8*)&hhiL[mm][q*8];
    s16x8 hhi1=*(const s16x8*)&hhiL[mm][32+q*8];
    s16x8 hlo0=*(const s16x8*)&hloL[mm][q*8];
    s16x8 hlo1=*(const s16x8*)&hloL[mm][32+q*8];

    f32x4 ar0={0.0f,0.0f,0.0f,0.0f}, ar1={0.0f,0.0f,0.0f,0.0f};
    f32x4 az0={0.0f,0.0f,0.0f,0.0f}, az1={0.0f,0.0f,0.0f,0.0f};
    ar0=MFMA16(xf0 ,wgr[0],ar0); az0=MFMA16(xf0 ,wgz[0],az0);
    ar0=MFMA16(xf1 ,wgr[1],ar0); az0=MFMA16(xf1 ,wgz[1],az0);
    ar0=MFMA16(hhi0,wgr[2],ar0); az0=MFMA16(hhi0,wgz[2],az0);
    ar1=MFMA16(hhi1,wgr[3],ar1); az1=MFMA16(hhi1,wgz[3],az1);
    ar1=MFMA16(hlo0,wgr[2],ar1); az1=MFMA16(hlo0,wgz[2],az1);
    ar1=MFMA16(hlo1,wgr[3],ar1); az1=MFMA16(hlo1,wgz[3],az1);
    f32x4 ar=ar0+ar1, az=az0+az1;

    float zs[4];
#pragma unroll
    for (int r=0;r<4;r++){
      float rg=sigm(ar[r]+bgr);
      float pv=rg*hreg[r];
      u16 ph=(u16)(__float_as_uint(pv)>>16);
      phiL[q*4+r][16*w+mm]=ph;
      ploL[q*4+r][16*w+mm]=f2bf(pv-bf2f(ph));
      zs[r]=sigm(az[r]+bgz);
    }
    __syncthreads();

    s16x8 phi0=*(const s16x8*)&phiL[mm][q*8];
    s16x8 phi1=*(const s16x8*)&phiL[mm][32+q*8];
    s16x8 plo0=*(const s16x8*)&ploL[mm][q*8];
    s16x8 plo1=*(const s16x8*)&ploL[mm][32+q*8];

    f32x4 ac0={0.0f,0.0f,0.0f,0.0f}, ac1={0.0f,0.0f,0.0f,0.0f};
    ac0=MFMA16(xf0 ,wcf[0],ac0);
    ac0=MFMA16(xf1 ,wcf[1],ac0);
    ac0=MFMA16(phi0,wcf[2],ac0);
    ac1=MFMA16(phi1,wcf[3],ac1);
    ac1=MFMA16(plo0,wcf[2],ac1);
    ac1=MFMA16(plo1,wcf[3],ac1);
    f32x4 ac=ac0+ac1;
#pragma unroll
    for (int r=0;r<4;r++){
      float c=tanh_(ac[r]+bcv);
      float hn=zs[r]*hreg[r]+(1.0f-zs[r])*c;
      if (t>=lenq[r]) hn=hreg[r];
      hreg[r]=hn;
      u16 hh=f2bf(hn);
      hhiL[q*4+r][16*w+mm]=hh;
      hloL[q*4+r][16*w+mm]=f2bf(hn-bf2f(hh));
    }
    __syncthreads();
    xf0=nx0; xf1=nx1;
  }

#pragma unroll
  for (int r=0;r<4;r++)
    f2[(size_t)(b0+q*4+r)*64 + 16*w+mm]=hreg[r];
}

// ---------------- fcn: [ue|ie|hs|ie*hs|f2] (320) -> 128 -> 40 -> 1 ----------------
__global__ __launch_bounds__(64,1) void fcn_kernel(
    const int* __restrict__ uidx, const int* __restrict__ iidx,
    const float* __restrict__ uemb, const float* __restrict__ emb,
    const float* __restrict__ hs, const float* __restrict__ f2,
    const float* __restrict__ Wf1, const float* __restrict__ fb1, const float* __restrict__ fp1,
    const float* __restrict__ Wf2, const float* __restrict__ fb2, const float* __restrict__ fp2,
    const float* __restrict__ Wf3, const float* __restrict__ fb3,
    float* __restrict__ out)
{
  __shared__ float inL[16][320];
  __shared__ __attribute__((aligned(16))) u16 h1L[16][128];
  __shared__ float h2o[16][40];
  const int lane=threadIdx.x, q=lane>>4, mm=lane&15;
  const int b0=blockIdx.x*16;

  {
    int row=lane>>2, sub=lane&3;
    int b=b0+row;
    int ub=uidx[b], ibv=iidx[b];
    for (int c=sub*80;c<sub*80+80;c++){
      int seg=c>>6, f=c&63; float v;
      if      (seg==0) v=uemb[(size_t)ub*64+f];
      else if (seg==1) v=emb[(size_t)ibv*64+f];
      else if (seg==2) v=hs[(size_t)b*64+f];
      else if (seg==3) v=emb[(size_t)ibv*64+f]*hs[(size_t)b*64+f];
      else             v=f2[(size_t)b*64+f];
      inL[row][c]=v;
    }
  }
  __syncthreads();

  {
    f32x4 acc1[8];
#pragma unroll
    for (int nt=0;nt<8;nt++) acc1[nt]=f32x4{0.0f,0.0f,0.0f,0.0f};
#pragma unroll
    for (int kc=0;kc<10;kc++){
      s16x8 af;
#pragma unroll
      for (int j=0;j<8;j++) af[j]=(short)f2bf(inL[mm][32*kc+q*8+j]);
#pragma unroll
      for (int nt=0;nt<8;nt++){
        s16x8 bfr;
#pragma unroll
        for (int j=0;j<8;j++) bfr[j]=(short)f2bf(Wf1[(size_t)(32*kc+q*8+j)*128 + 16*nt+mm]);
        acc1[nt]=MFMA16(af,bfr,acc1[nt]);
      }
    }
#pragma unroll
    for (int nt=0;nt<8;nt++)
#pragma unroll
      for (int r=0;r<4;r++){
        int col=16*nt+mm, row=q*4+r;
        float x=acc1[nt][r]+fb1[col];
        float pp=fp1[col];
        h1L[row][col]=f2bf((x>=0.0f)?x:pp*x);
      }
  }
  __syncthreads();

  {
    f32x4 acc2[3];
#pragma unroll
    for (int nt=0;nt<3;nt++) acc2[nt]=f32x4{0.0f,0.0f,0.0f,0.0f};
#pragma unroll
    for (int kc=0;kc<4;kc++){
      s16x8 af=*(const s16x8*)&h1L[mm][32*kc+q*8];
#pragma unroll
      for (int nt=0;nt<3;nt++){
        s16x8 bfr;
#pragma unroll
        for (int j=0;j<8;j++){
          int k=32*kc+q*8+j, n=16*nt+mm;
          bfr[j]=(short)((n<40)?f2bf(Wf2[(size_t)k*40+n]):0);
        }
        acc2[nt]=MFMA16(af,bfr,acc2[nt]);
      }
    }
#pragma unroll
    for (int nt=0;nt<3;nt++)
#pragma unroll
      for (int r=0;r<4;r++){
        int col=16*nt+mm, row=q*4+r;
        if (col<40){
          float x=acc2[nt][r]+fb2[col];
          float pp=fp2[col];
          h2o[row][col]=(x>=0.0f)?x:pp*x;
        }
      }
  }
  __syncthreads();

  {
    int row=lane>>2, sub=lane&3;
    float s=0.0f;
    for (int k=sub;k<40;k+=4) s+=h2o[row][k]*Wf3[k];
    s+=__shfl_xor(s,1); s+=__shfl_xor(s,2);
    if (sub==0) out[b0+row]=s+fb3[0];
  }
}

// ================================================================
// FALLBACK (zero workspace): the R4 mega kernel, f32 path proven
// ================================================================
template<bool F32>
__global__ __launch_bounds__(64,1) void dien_mega_kernel(
    const int* __restrict__ uidx, const int* __restrict__ iidx,
    const int* __restrict__ hist, const void* __restrict__ mask,
    const void* __restrict__ emb,  const void* __restrict__ uemb,
    const void* __restrict__ W1g, const void* __restrict__ U1g, const void* __restrict__ g1bg,
    const void* __restrict__ W1c, const void* __restrict__ U1c, const void* __restrict__ g1bc,
    const void* __restrict__ Wa1, const void* __restrict__ ba1,
    const void* __restrict__ Wa2, const void* __restrict__ ba2,
    const void* __restrict__ Wa3, const void* __restrict__ ba3,
    const void* __restrict__ W2g, const void* __restrict__ U2g, const void* __restrict__ g2bg,
    const void* __restrict__ W2c, const void* __restrict__ U2c, const void* __restrict__ g2bc,
    const void* __restrict__ Wf1, const void* __restrict__ fb1, const void* __restrict__ fp1,
    const void* __restrict__ Wf2, const void* __restrict__ fb2, const void* __restrict__ fp2,
    const void* __restrict__ Wf3, const void* __restrict__ fb3,
    void* __restrict__ outp)
{
  auto LF=[&](const void* p, size_t i)->float {
    return F32 ? ((const float*)p)[i] : bf2f(((const u16*)p)[i]);
  };
  auto LB=[&](const void* p, size_t i)->u16 {
    return F32 ? f2bf(((const float*)p)[i]) : ((const u16*)p)[i];
  };
  auto FR8=[&](const void* p, size_t off)->s16x8 {
    s16x8 f;
    if (F32){
      const float* pp=(const float*)p+off;
      f32x4 a=*(const f32x4*)pp, b=*(const f32x4*)(pp+4);
#pragma unroll
      for (int j=0;j<4;j++){ f[j]=(short)f2bf(a[j]); f[j+4]=(short)f2bf(b[j]); }
    } else {
      f=*(const s16x8*)((const u16*)p+off);
    }
    return f;
  };

  __shared__ float h1buf[16][68];
  __shared__ float h2buf[16][68];
  __shared__ float pbuf [16][68];
  __shared__ u16   d1buf[16][104];
  __shared__ u16   scL  [16][200];
  __shared__ float hsL  [16][64];
  __shared__ s16x8 u2gL [16][64];
  __shared__ s16x8 u2cL [ 8][64];
  __shared__ float h2o  [16][40];
  __shared__ u16   ueL  [16][64];
  __shared__ u16   ieL  [16][64];
  __shared__ int   lenL [16];

  const int lane=threadIdx.x, q=lane>>4, mm=lane&15;
  const int g=blockIdx.x, b0=g*16;
  const int pb_m=b0+mm;

  {
    int cnt=0;
    for (int t=q*50;t<q*50+50;t++) cnt += (LF(mask,(size_t)pb_m*TT+t)!=0.0f);
    cnt += __shfl_xor(cnt,16);
    cnt += __shfl_xor(cnt,32);
    if (lane<16) lenL[lane]=cnt;
  }
  __syncthreads();
  int lenq[4];
#pragma unroll
  for (int r=0;r<4;r++) lenq[r]=lenL[q*4+r];
  int maxlen=1;
  for (int i=0;i<16;i++) maxlen = (lenL[i]>maxlen)?lenL[i]:maxlen;

  s16x8 wgt[8][4];
#pragma unroll
  for (int nt=0;nt<8;nt++)
#pragma unroll
    for (int c=0;c<4;c++){
      s16x8 f;
#pragma unroll
      for (int j=0;j<8;j++){
        int k=32*c+q*8+j, n=16*nt+mm;
        f[j]=(short)((k<64)?LB(W1g,(size_t)k*128+n):LB(U1g,(size_t)(k-64)*128+n));
      }
      wgt[nt][c]=f;
    }
  s16x8 wct[4][4];
#pragma unroll
  for (int nt=0;nt<4;nt++)
#pragma unroll
    for (int c=0;c<4;c++){
      s16x8 f;
#pragma unroll
      for (int j=0;j<8;j++){
        int k=32*c+q*8+j, n=16*nt+mm;
        f[j]=(short)((k<64)?LB(W1c,(size_t)k*64+n):LB(U1c,(size_t)(k-64)*64+n));
      }
      wct[nt][c]=f;
    }
  float b1gv[8], b1cv[4];
#pragma unroll
  for (int nt=0;nt<8;nt++) b1gv[nt]=LF(g1bg,16*nt+mm);
#pragma unroll
  for (int nt=0;nt<4;nt++) b1cv[nt]=LF(g1bc,16*nt+mm);

  s16x8 w1k[5][2], wd[5][2];
#pragma unroll
  for (int nt=0;nt<5;nt++)
#pragma unroll
    for (int c=0;c<2;c++){
      s16x8 f1,f2;
#pragma unroll
      for (int j=0;j<8;j++){
        int k=32*c+q*8+j, n=16*nt+mm;
        f1[j]=(short)f2bf(LF(Wa1,(size_t)(64+k)*80+n) - LF(Wa1,(size_t)(128+k)*80+n));
        f2[j]=(short)LB(Wa1,(size_t)(192+k)*80+n);
      }
      w1k[nt][c]=f1; wd[nt][c]=f2;
    }
  s16x8 w2f[3][3];
#pragma unroll
  for (int nt=0;nt<3;nt++)
#pragma unroll
    for (int c=0;c<3;c++){
      s16x8 f;
#pragma unroll
      for (int j=0;j<8;j++){
        int k=32*c+q*8+j, n=16*nt+mm;
        f[j]=(short)((k<80 && n<40)?LB(Wa2,(size_t)k*40+n):0);
      }
      w2f[nt][c]=f;
    }
  float ba2v[3], w3v[3];
#pragma unroll
  for (int nt=0;nt<3;nt++){ int n=16*nt+mm; ba2v[nt]=(n<40)?LF(ba2,n):0.0f; w3v[nt]=(n<40)?LF(Wa3,n):0.0f; }
  const float ba3v=LF(ba3,0);

  const int ib=iidx[pb_m];
  const s16x8 qf0=FR8(emb,(size_t)ib*64+q*8);
  const s16x8 qf1=FR8(emb,(size_t)ib*64+32+q*8);

  f32x4 pre[5];
#pragma unroll
  for (int nt=0;nt<5;nt++){
    f32x4 a={0.0f,0.0f,0.0f,0.0f};
#pragma unroll
    for (int c=0;c<2;c++){
      s16x8 f;
#pragma unroll
      for (int j=0;j<8;j++){
        int k=32*c+q*8+j, n=16*nt+mm;
        f[j]=(short)f2bf(LF(Wa1,(size_t)k*80+n) + LF(Wa1,(size_t)(128+k)*80+n));
      }
      a=MFMA16((c==0)?qf0:qf1, f, a);
    }
    float bb=LF(ba1,16*nt+mm);
#pragma unroll
    for (int r=0;r<4;r++) a[r]+=bb;
    pre[nt]=a;
  }

  for (int ii=lane; ii<16*68; ii+=64){ (&h1buf[0][0])[ii]=0.0f; (&h2buf[0][0])[ii]=0.0f; }
  for (int ii=lane; ii<16*104; ii+=64) (&d1buf[0][0])[ii]=0;
  __syncthreads();

  auto load_x=[&](int t, s16x8 &a0, s16x8 &a1){
    int idx = hist[(size_t)pb_m*TT+t];
    a0 = FR8(emb,(size_t)idx*64+q*8);
    a1 = FR8(emb,(size_t)idx*64+32+q*8);
  };

  float hsA[8], hsB[8];
#pragma unroll
  for (int j=0;j<8;j++){ hsA[j]=0.0f; hsB[j]=0.0f; }

  s16x8 xf0,xf1;
  load_x(0,xf0,xf1);
  for (int t=0;t<maxlen;t++){
    s16x8 nx0,nx1;
    { int tn=(t+1<maxlen)?(t+1):(maxlen-1); load_x(tn,nx0,nx1); }

#pragma unroll
    for (int j=0;j<8;j++){ hsA[j]+=bf2f((u16)xf0[j]); hsB[j]+=bf2f((u16)xf1[j]); }

    f32x4 hA0=*(const f32x4*)&h1buf[mm][q*8];
    f32x4 hA1=*(const f32x4*)&h1buf[mm][q*8+4];
    f32x4 hB0=*(const f32x4*)&h1buf[mm][32+q*8];
    f32x4 hB1=*(const f32x4*)&h1buf[mm][32+q*8+4];
    s16x8 hhi0,hlo0,hhi1,hlo1;
    split8(hA0,hA1,hhi0,hlo0);
    split8(hB0,hB1,hhi1,hlo1);

    f32x4 ga[8];
#pragma unroll
    for (int nt=0;nt<8;nt++){
      f32x4 a={0.0f,0.0f,0.0f,0.0f};
      a=MFMA16(xf0 ,wgt[nt][0],a);
      a=MFMA16(xf1 ,wgt[nt][1],a);
      a=MFMA16(hhi0,wgt[nt][2],a);
      a=MFMA16(hhi1,wgt[nt][3],a);
      a=MFMA16(hlo0,wgt[nt][2],a);
      a=MFMA16(hlo1,wgt[nt][3],a);
      ga[nt]=a;
    }
    float zs[4][4], hv[4][4];
#pragma unroll
    for (int nt=0;nt<4;nt++)
#pragma unroll
      for (int r=0;r<4;r++){
        float rg=sigm(ga[nt][r]+b1gv[nt]);
        float h_=h1buf[q*4+r][16*nt+mm];
        hv[nt][r]=h_;
        pbuf[q*4+r][16*nt+mm]=rg*h_;
        zs[nt][r]=sigm(ga[nt+4][r]+b1gv[nt+4]);
      }
    __syncthreads();

    f32x4 pA0=*(const f32x4*)&pbuf[mm][q*8];
    f32x4 pA1=*(const f32x4*)&pbuf[mm][q*8+4];
    f32x4 pB0=*(const f32x4*)&pbuf[mm][32+q*8];
    f32x4 pB1=*(const f32x4*)&pbuf[mm][32+q*8+4];
    s16x8 phi0,plo0,phi1,plo1;
    split8(pA0,pA1,phi0,plo0);
    split8(pB0,pB1,phi1,plo1);

    f32x4 ca[4];
#pragma unroll
    for (int nt=0;nt<4;nt++){
      f32x4 a={0.0f,0.0f,0.0f,0.0f};
      a=MFMA16(xf0 ,wct[nt][0],a);
      a=MFMA16(xf1 ,wct[nt][1],a);
      a=MFMA16(phi0,wct[nt][2],a);
      a=MFMA16(phi1,wct[nt][3],a);
      a=MFMA16(plo0,wct[nt][2],a);
      a=MFMA16(plo1,wct[nt][3],a);
      ca[nt]=a;
    }
#pragma unroll
    for (int nt=0;nt<4;nt++)
#pragma unroll
      for (int r=0;r<4;r++){
        float c=tanh_(ca[nt][r]+b1cv[nt]);
        float z=zs[nt][r];
        float hn=z*hv[nt][r]+(1.0f-z)*c;
        if (t>=lenq[r]) hn=hv[nt][r];
        h1buf[q*4+r][16*nt+mm]=hn;
      }
    __syncthreads();

    f32x4 k0a=*(const f32x4*)&h1buf[mm][q*8];
    f32x4 k0b=*(const f32x4*)&h1buf[mm][q*8+4];
    f32x4 k1a=*(const f32x4*)&h1buf[mm][32+q*8];
    f32x4 k1b=*(const f32x4*)&h1buf[mm][32+q*8+4];
    s16x8 kf0,kf1,kq0,kq1;
#pragma unroll
    for (int j=0;j<4;j++){
      kf0[j]  =(short)f2bf(k0a[j]);  kf0[j+4]=(short)f2bf(k0b[j]);
      kf1[j]  =(short)f2bf(k1a[j]);  kf1[j+4]=(short)f2bf(k1b[j]);
      kq0[j]  =(short)f2bf(k0a[j]*bf2f((u16)qf0[j]));
      kq0[j+4]=(short)f2bf(k0b[j]*bf2f((u16)qf0[j+4]));
      kq1[j]  =(short)f2bf(k1a[j]*bf2f((u16)qf1[j]));
      kq1[j+4]=(short)f2bf(k1b[j]*bf2f((u16)qf1[j+4]));
    }
    f32x4 acc[5];
#pragma unroll
    for (int nt=0;nt<5;nt++){
      f32x4 a=pre[nt];
      a=MFMA16(kf0,w1k[nt][0],a); a=MFMA16(kf1,w1k[nt][1],a);
      a=MFMA16(kq0,wd[nt][0],a);  a=MFMA16(kq1,wd[nt][1],a);
      acc[nt]=a;
    }
#pragma unroll
    for (int nt=0;nt<5;nt++)
#pragma unroll
      for (int r=0;r<4;r++)
        d1buf[q*4+r][16*nt+mm]=f2bf(sigm(acc[nt][r]));
    __syncthreads();
    s16x8 a0=*(const s16x8*)&d1buf[mm][q*8];
    s16x8 a1=*(const s16x8*)&d1buf[mm][32+q*8];
    s16x8 a2=*(const s16x8*)&d1buf[mm][64+q*8];
    f32x4 acc2[3];
#pragma unroll
    for (int nt=0;nt<3;nt++){
      f32x4 a={0.0f,0.0f,0.0f,0.0f};
      a=MFMA16(a0,w2f[nt][0],a); a=MFMA16(a1,w2f[nt][1],a); a=MFMA16(a2,w2f[nt][2],a);
      acc2[nt]=a;
    }
    float part[4];
#pragma unroll
    for (int r=0;r<4;r++){
      float sacc=0.0f;
#pragma unroll
      for (int nt=0;nt<3;nt++) sacc+=sigm(acc2[nt][r]+ba2v[nt])*w3v[nt];
      part[r]=sacc;
    }
#pragma unroll
    for (int d=1;d<16;d<<=1)
#pragma unroll
      for (int r=0;r<4;r++) part[r]+=__shfl_xor(part[r],d);
    if (mm==0){
#pragma unroll
      for (int r=0;r<4;r++) scL[q*4+r][t]=f2bf(part[r]+ba3v);
    }
    __syncthreads();

    xf0=nx0; xf1=nx1;
  }

  for (int t=maxlen;t<TT;t++){
    s16x8 a0,a1; load_x(t,a0,a1);
#pragma unroll
    for (int j=0;j<8;j++){ hsA[j]+=bf2f((u16)a0[j]); hsB[j]+=bf2f((u16)a1[j]); }
  }
#pragma unroll
  for (int j=0;j<8;j++){ hsL[mm][q*8+j]=hsA[j]; hsL[mm][32+q*8+j]=hsB[j]; }
  __syncthreads();

  {
    int row=lane>>2, sub=lane&3;
    int L=lenL[row];
    float mx=-3e38f;
    for (int t=sub;t<L;t+=4) mx=fmaxf(mx,bf2f(scL[row][t]));
    mx=fmaxf(mx,__shfl_xor(mx,1)); mx=fmaxf(mx,__shfl_xor(mx,2));
    float sm=0.0f;
    for (int t=sub;t<L;t+=4) sm+=__expf(bf2f(scL[row][t])-mx);
    sm+=__shfl_xor(sm,1); sm+=__shfl_xor(sm,2);
    float inv=1.0f/sm;
    for (int t=sub;t<TT;t+=4){
      float v=(t<L)?(__expf(bf2f(scL[row][t])-mx)*inv):0.0f;
      scL[row][t]=f2bf(v);
    }
  }
  __syncthreads();

  s16x8 wg2x[8][2], wc2x[4][2];
#pragma unroll
  for (int nt=0;nt<8;nt++)
#pragma unroll
    for (int c=0;c<2;c++){
      s16x8 f,fh;
#pragma unroll
      for (int j=0;j<8;j++){
        int k=32*c+q*8+j, n=16*nt+mm;
        f[j] =(short)LB(W2g,(size_t)k*128+n);
        fh[j]=(short)LB(U2g,(size_t)k*128+n);
      }
      wg2x[nt][c]=f;
      u2gL[nt*2+c][lane]=fh;
    }
#pragma unroll
  for (int nt=0;nt<4;nt++)
#pragma unroll
    for (int c=0;c<2;c++){
      s16x8 f,fh;
#pragma unroll
      for (int j=0;j<8;j++){
        int k=32*c+q*8+j, n=16*nt+mm;
        f[j] =(short)LB(W2c,(size_t)k*64+n);
        fh[j]=(short)LB(U2c,(size_t)k*64+n);
      }
      wc2x[nt][c]=f;
      u2cL[nt*2+c][lane]=fh;
    }
  float b2gv[8], b2cv[4];
#pragma unroll
  for (int nt=0;nt<8;nt++) b2gv[nt]=LF(g2bg,16*nt+mm);
#pragma unroll
  for (int nt=0;nt<4;nt++) b2cv[nt]=LF(g2bc,16*nt+mm);

  for (int ii=lane; ii<16*68; ii+=64){ (&h1buf[0][0])[ii]=0.0f; (&h2buf[0][0])[ii]=0.0f; }
  __syncthreads();

  load_x(0,xf0,xf1);
  for (int t=0;t<maxlen;t++){
    s16x8 nx0,nx1;
    { int tn=(t+1<maxlen)?(t+1):(maxlen-1); load_x(tn,nx0,nx1); }

    {
      f32x4 hA0=*(const f32x4*)&h1buf[mm][q*8];
      f32x4 hA1=*(const f32x4*)&h1buf[mm][q*8+4];
      f32x4 hB0=*(const f32x4*)&h1buf[mm][32+q*8];
      f32x4 hB1=*(const f32x4*)&h1buf[mm][32+q*8+4];
      s16x8 hhi0,hlo0,hhi1,hlo1;
      split8(hA0,hA1,hhi0,hlo0);
      split8(hB0,hB1,hhi1,hlo1);
      f32x4 ga[8];
#pragma unroll
      for (int nt=0;nt<8;nt++){
        f32x4 a={0.0f,0.0f,0.0f,0.0f};
        a=MFMA16(xf0 ,wgt[nt][0],a);
        a=MFMA16(xf1 ,wgt[nt][1],a);
        a=MFMA16(hhi0,wgt[nt][2],a);
        a=MFMA16(hhi1,wgt[nt][3],a);
        a=MFMA16(hlo0,wgt[nt][2],a);
        a=MFMA16(hlo1,wgt[nt][3],a);
        ga[nt]=a;
      }
      float zs[4][4], hv[4][4];
#pragma unroll
      for (int nt=0;nt<4;nt++)
#pragma unroll
        for (int r=0;r<4;r++){
          float rg=sigm(ga[nt][r]+b1gv[nt]);
          float h_=h1buf[q*4+r][16*nt+mm];
          hv[nt][r]=h_;
          pbuf[q*4+r][16*nt+mm]=rg*h_;
          zs[nt][r]=sigm(ga[nt+4][r]+b1gv[nt+4]);
        }
      __syncthreads();
      f32x4 pA0=*(const f32x4*)&pbuf[mm][q*8];
      f32x4 pA1=*(const f32x4*)&pbuf[mm][q*8+4];
      f32x4 pB0=*(const f32x4*)&pbuf[mm][32+q*8];
      f32x4 pB1=*(const f32x4*)&pbuf[mm][32+q*8+4];
      s16x8 phi0,plo0,phi1,plo1;
      split8(pA0,pA1,phi0,plo0);
      split8(pB0,pB1,phi1,plo1);
      f32x4 ca[4];
#pragma unroll
      for (int nt=0;nt<4;nt++){
        f32x4 a={0.0f,0.0f,0.0f,0.0f};
        a=MFMA16(xf0 ,wct[nt][0],a);
        a=MFMA16(xf1 ,wct[nt][1],a);
        a=MFMA16(phi0,wct[nt][2],a);
        a=MFMA16(phi1,wct[nt][3],a);
        a=MFMA16(plo0,wct[nt][2],a);
        a=MFMA16(plo1,wct[nt][3],a);
        ca[nt]=a;
      }
#pragma unroll
      for (int nt=0;nt<4;nt++)
#pragma unroll
        for (int r=0;r<4;r++){
          float c=tanh_(ca[nt][r]+b1cv[nt]);
          float z=zs[nt][r];
          float hn=z*hv[nt][r]+(1.0f-z)*c;
          if (t>=lenq[r]) hn=hv[nt][r];
          h1buf[q*4+r][16*nt+mm]=hn;
        }
      __syncthreads();
    }

    {
      float al=bf2f(scL[mm][t]);
      f32x4 x0a=*(const f32x4*)&h1buf[mm][q*8];
      f32x4 x0b=*(const f32x4*)&h1buf[mm][q*8+4];
      f32x4 x1a=*(const f32x4*)&h1buf[mm][32+q*8];
      f32x4 x1b=*(const f32x4*)&h1buf[mm][32+q*8+4];
      s16x8 af0,af1;
#pragma unroll
      for (int j=0;j<4;j++){
        af0[j]  =(short)f2bf(x0a[j]*al); af0[j+4]=(short)f2bf(x0b[j]*al);
        af1[j]  =(short)f2bf(x1a[j]*al); af1[j+4]=(short)f2bf(x1b[j]*al);
      }
      f32x4 hA0=*(const f32x4*)&h2buf[mm][q*8];
      f32x4 hA1=*(const f32x4*)&h2buf[mm][q*8+4];
      f32x4 hB0=*(const f32x4*)&h2buf[mm][32+q*8];
      f32x4 hB1=*(const f32x4*)&h2buf[mm][32+q*8+4];
      s16x8 hhi0,hlo0,hhi1,hlo1;
      split8(hA0,hA1,hhi0,hlo0);
      split8(hB0,hB1,hhi1,hlo1);
      f32x4 ga[8];
#pragma unroll
      for (int nt=0;nt<8;nt++){
        s16x8 wh0=u2gL[nt*2+0][lane];
        s16x8 wh1=u2gL[nt*2+1][lane];
        f32x4 a={0.0f,0.0f,0.0f,0.0f};
        a=MFMA16(af0 ,wg2x[nt][0],a);
        a=MFMA16(af1 ,wg2x[nt][1],a);
        a=MFMA16(hhi0,wh0,a);
        a=MFMA16(hhi1,wh1,a);
        a=MFMA16(hlo0,wh0,a);
        a=MFMA16(hlo1,wh1,a);
        ga[nt]=a;
      }
      float zs[4][4], hv[4][4];
#pragma unroll
      for (int nt=0;nt<4;nt++)
#pragma unroll
        for (int r=0;r<4;r++){
          float rg=sigm(ga[nt][r]+b2gv[nt]);
          float h_=h2buf[q*4+r][16*nt+mm];
          hv[nt][r]=h_;
          pbuf[q*4+r][16*nt+mm]=rg*h_;
          zs[nt][r]=sigm(ga[nt+4][r]+b2gv[nt+4]);
        }
      __syncthreads();
      f32x4 pA0=*(const f32x4*)&pbuf[mm][q*8];
      f32x4 pA1=*(const f32x4*)&pbuf[mm][q*8+4];
      f32x4 pB0=*(const f32x4*)&pbuf[mm][32+q*8];
      f32x4 pB1=*(const f32x4*)&pbuf[mm][32+q*8+4];
      s16x8 phi0,plo0,phi1,plo1;
      split8(pA0,pA1,phi0,plo0);
      split8(pB0,pB1,phi1,plo1);
      f32x4 ca[4];
#pragma unroll
      for (int nt=0;nt<4;nt++){
        s16x8 wh0=u2cL[nt*2+0][lane];
        s16x8 wh1=u2cL[nt*2+1][lane];
        f32x4 a={0.0f,0.0f,0.0f,0.0f};
        a=MFMA16(af0 ,wc2x[nt][0],a);
        a=MFMA16(af1 ,wc2x[nt][1],a);
        a=MFMA16(phi0,wh0,a);
        a=MFMA16(phi1,wh1,a);
        a=MFMA16(plo0,wh0,a);
        a=MFMA16(plo1,wh1,a);
        ca[nt]=a;
      }
#pragma unroll
      for (int nt=0;nt<4;nt++)
#pragma unroll
        for (int r=0;r<4;r++){
          float c=tanh_(ca[nt][r]+b2cv[nt]);
          float z=zs[nt][r];
          float hn=z*hv[nt][r]+(1.0f-z)*c;
          if (t>=lenq[r]) hn=hv[nt][r];
          h2buf[q*4+r][16*nt+mm]=hn;
        }
      __syncthreads();
    }

    xf0=nx0; xf1=nx1;
  }

  {
    int row=lane>>2, c0=(lane&3)*16;
    int ub=uidx[b0+row], ibv=iidx[b0+row];
#pragma unroll
    for (int j=0;j<16;j++){
      ueL[row][c0+j]=LB(uemb,(size_t)ub*64+c0+j);
      ieL[row][c0+j]=LB(emb ,(size_t)ibv*64+c0+j);
    }
  }
  __syncthreads();

  {
    f32x4 acc1[8];
#pragma unroll
    for (int nt=0;nt<8;nt++) acc1[nt]=f32x4{0.0f,0.0f,0.0f,0.0f};
#pragma unroll
    for (int kc=0;kc<10;kc++){
      const int seg=kc>>1, off=(kc&1)*32+q*8;
      s16x8 af;
#pragma unroll
      for (int j=0;j<8;j++){
        int f=off+j;
        u16 v;
        if      (seg==0) v=ueL[mm][f];
        else if (seg==1) v=ieL[mm][f];
        else if (seg==2) v=f2bf(hsL[mm][f]);
        else if (seg==3) v=f2bf(bf2f(ieL[mm][f])*hsL[mm][f]);
        else             v=f2bf(h2buf[mm][f]);
        af[j]=(short)v;
      }
#pragma unroll
      for (int nt=0;nt<8;nt++){
        s16x8 bfr;
#pragma unroll
        for (int j=0;j<8;j++) bfr[j]=(short)LB(Wf1,(size_t)(32*kc+q*8+j)*128 + 16*nt+mm);
        acc1[nt]=MFMA16(af,bfr,acc1[nt]);
      }
    }
    __syncthreads();
#pragma unroll
    for (int nt=0;nt<8;nt++)
#pragma unroll
      for (int r=0;r<4;r++){
        int col=16*nt+mm, row=q*4+r;
        float x=acc1[nt][r]+LF(fb1,col);
        float pp=LF(fp1,col);
        scL[row][col]=f2bf((x>=0.0f)?x:pp*x);
      }
  }
  __syncthreads();

  {
    f32x4 acc2[3];
#pragma unroll
    for (int nt=0;nt<3;nt++) acc2[nt]=f32x4{0.0f,0.0f,0.0f,0.0f};
#pragma unroll
    for (int kc=0;kc<4;kc++){
      s16x8 af=*(const s16x8*)&scL[mm][32*kc+q*8];
#pragma unroll
      for (int nt=0;nt<3;nt++){
        s16x8 bfr;
#pragma unroll
        for (int j=0;j<8;j++){
          int k=32*kc+q*8+j, n=16*nt+mm;
          bfr[j]=(short)((n<40)?LB(Wf2,(size_t)k*40+n):0);
        }
        acc2[nt]=MFMA16(af,bfr,acc2[nt]);
      }
    }
#pragma unroll
    for (int nt=0;nt<3;nt++)
#pragma unroll
      for (int r=0;r<4;r++){
        int col=16*nt+mm, row=q*4+r;
        if (col<40){
          float x=acc2[nt][r]+LF(fb2,col);
          float pp=LF(fp2,col);
          h2o[row][col]=(x>=0.0f)?x:pp*x;
        }
      }
  }
  __syncthreads();

  {
    int row=lane>>2, sub=lane&3;
    float s=0.0f;
    for (int k=sub;k<40;k+=4) s+=h2o[row][k]*LF(Wf3,k);
    s+=__shfl_xor(s,1); s+=__shfl_xor(s,2);
    if (sub==0){
      float v=s+LF(fb3,0);
      if (F32) ((float*)outp)[b0+row]=v;
      else     ((u16*) outp)[b0+row]=f2bf(v);
    }
  }
}

extern "C" void kernel_launch(void* const* d_in, const int* in_sizes, int n_in,
                              void* d_out, int out_size, void* d_ws, size_t ws_size,
                              hipStream_t stream)
{
  (void)n_in; (void)out_size;
  const int* u    =(const int*)d_in[0];
  const int* it   =(const int*)d_in[1];
  const int* hist =(const int*)d_in[2];
  const float* mask=(const float*)d_in[3];
  const float* item_emb=(const float*)d_in[4];
  const float* user_emb=(const float*)d_in[5];
  const float* g1Wg=(const float*)d_in[6],  *g1Ug=(const float*)d_in[7],  *g1bg=(const float*)d_in[8];
  const float* g1Wc=(const float*)d_in[9],  *g1Uc=(const float*)d_in[10], *g1bc=(const float*)d_in[11];
  const float* Wa1=(const float*)d_in[12], *ba1=(const float*)d_in[13];
  const float* Wa2=(const float*)d_in[14], *ba2=(const float*)d_in[15];
  const float* Wa3=(const float*)d_in[16], *ba3=(const float*)d_in[17];
  const float* g2Wg=(const float*)d_in[18], *g2Ug=(const float*)d_in[19], *g2bg=(const float*)d_in[20];
  const float* g2Wc=(const float*)d_in[21], *g2Uc=(const float*)d_in[22], *g2bc=(const float*)d_in[23];
  const float* W1=(const float*)d_in[24], *b1=(const float*)d_in[25], *p1=(const float*)d_in[26];
  const float* W2=(const float*)d_in[27], *b2=(const float*)d_in[28], *p2=(const float*)d_in[29];
  const float* W3=(const float*)d_in[30], *b3=(const float*)d_in[31];

  const int emb_n = in_sizes[4];                       // N_ITEM*64
  const size_t sz_rnn1 =(size_t)BB*TT*64*2;
  const size_t sz_attin=(size_t)BB*TT*64*2;
  const size_t sz_emb16=(((size_t)emb_n*2)+255)&~(size_t)255;
  const size_t sz_len  =(((size_t)BB*4)+255)&~(size_t)255;
  const size_t sz_hs   =(size_t)BB*64*4;
  const size_t sz_f2   =(size_t)BB*64*4;
  const size_t NEED = sz_rnn1+sz_attin+sz_emb16+sz_len+sz_hs+sz_f2 + 1024;

  if (ws_size >= NEED){
    char* ws=(char*)d_ws;
    u16*   rnn1 =(u16*)ws;   ws+=sz_rnn1;
    u16*   attin=(u16*)ws;   ws+=sz_attin;
    u16*   emb16=(u16*)ws;   ws+=sz_emb16;
    int*   len_g=(int*)ws;   ws+=sz_len;
    float* hs   =(float*)ws; ws+=sz_hs;
    float* f2   =(float*)ws;

    conv_kernel    <<<(emb_n/8+255)/256,256,0,stream>>>(item_emb, emb16, emb_n);
    hist_sum_kernel<<<BB*8/256,256,0,stream>>>(hist, emb16, hs);
    scan1_kernel   <<<BB/16, 256, 0, stream>>>(hist, mask, emb16,
                                               g1Wg,g1Ug,g1bg,g1Wc,g1Uc,g1bc,
                                               len_g, rnn1);
    attn_kernel    <<<BB,     64, 0, stream>>>(it, item_emb, rnn1,
                                               Wa1,ba1,Wa2,ba2,Wa3,ba3,
                                               len_g, attin);
    scan2_kernel   <<<BB/16, 256, 0, stream>>>(attin, len_g,
                                               g2Wg,g2Ug,g2bg,g2Wc,g2Uc,g2bc,
                                               f2);
    fcn_kernel     <<<BB/16,  64, 0, stream>>>(u, it, user_emb, item_emb, hs, f2,
                                               W1,b1,p1,W2,b2,p2,W3,b3,
                                               (float*)d_out);
  } else {
    dien_mega_kernel<true><<<BB/16, 64, 0, stream>>>(
        u, it, hist, mask, item_emb, user_emb,
        g1Wg,g1Ug,g1bg,g1Wc,g1Uc,g1bc,
        Wa1,ba1,Wa2,ba2,Wa3,ba3,
        g2Wg,g2Ug,g2bg,g2Wc,g2Uc,g2bc,
        W1,b1,p1,W2,b2,p2,W3,b3,
        d_out);
  }
}

// Round 9
// 793.234 us; speedup vs baseline: 1.4817x; 1.1291x over previous
//
#include <hip/hip_runtime.h>

#define BB 4096
#define TT 200
// E = H = 64

typedef unsigned short u16;
typedef unsigned int   u32;
typedef unsigned short u16x8 __attribute__((ext_vector_type(8)));
typedef short s16x8 __attribute__((ext_vector_type(8)));
typedef float f32x4 __attribute__((ext_vector_type(4)));

__device__ __forceinline__ float bf2f(u16 u){ union{unsigned u; float f;} v; v.u=((unsigned)u)<<16; return v.f; }
__device__ __forceinline__ u16 f2bf(float f){ union{float f; unsigned u;} v; v.f=f; unsigned r=v.u + 0x7FFFu + ((v.u>>16)&1u); return (u16)(r>>16); }
__device__ __forceinline__ float sigm(float x){ return 1.0f/(1.0f+__expf(-x)); }
__device__ __forceinline__ float tanh_(float x){ return 1.0f - 2.0f/(1.0f+__expf(2.0f*x)); }

#define MFMA16(a,b,c) __builtin_amdgcn_mfma_f32_16x16x32_bf16((a),(b),(c),0,0,0)

// scalar split (fallback/mega path only). R6 measured v_cvt_pk_bf16_f32 slower — keep scalar.
__device__ __forceinline__ void split8(const f32x4 a, const f32x4 b, s16x8 &hi, s16x8 &lo){
#pragma unroll
  for (int j=0;j<4;j++){
    float v=a[j]; u16 h=(u16)(__float_as_uint(v)>>16);
    hi[j]=(short)h; lo[j]=(short)f2bf(v-bf2f(h));
    v=b[j]; h=(u16)(__float_as_uint(v)>>16);
    hi[j+4]=(short)h; lo[j+4]=(short)f2bf(v-bf2f(h));
  }
}

// ================================================================
// FAST PATH: conv(emb->bf16) -> hist_sum -> scan1 -> attn(+softmax,+attin) -> scan2 -> fcn
// Scans: 16 rows/block, 4-wave N-split, fp32 h state in registers,
// PURE-bf16 MFMA operand path (no hi/lo split): 12 MFMA/wave/step.
// ================================================================

// ---------------- item_emb fp32 -> bf16 table ----------------
__global__ void conv_kernel(const float* __restrict__ src, u16* __restrict__ dst, int n){
  int i=(blockIdx.x*256+threadIdx.x)*8;
  if (i>=n) return;
  f32x4 a=*(const f32x4*)(src+i), b=*(const f32x4*)(src+i+4);
  u16x8 o;
#pragma unroll
  for (int j=0;j<4;j++){ o[j]=f2bf(a[j]); o[j+4]=f2bf(b[j]); }
  *(u16x8*)(dst+i)=o;
}

// ---------------- hist_sum (unmasked, parallel; reads bf16 table) ----------------
__global__ void hist_sum_kernel(const int* __restrict__ hist, const u16* __restrict__ emb16,
                                float* __restrict__ hs){
  int tid = blockIdx.x*256 + threadIdx.x;     // B*8 threads
  int b = tid>>3, cg = (tid&7)*8;
  float acc[8];
#pragma unroll
  for (int j=0;j<8;j++) acc[j]=0.0f;
  for (int t=0;t<TT;t++){
    int idx = hist[(size_t)b*TT+t];
    u16x8 v=*(const u16x8*)(emb16+(size_t)idx*64+cg);
#pragma unroll
    for (int j=0;j<8;j++) acc[j]+=bf2f(v[j]);
  }
#pragma unroll
  for (int j=0;j<8;j++) hs[(size_t)b*64+cg+j]=acc[j];
}

// ---------------- scan1: gru1, 16 rows/block, pure-bf16 operands ----------------
__global__ __launch_bounds__(256,1) void scan1_kernel(
    const int* __restrict__ hist, const float* __restrict__ mask, const u16* __restrict__ emb16,
    const float* __restrict__ Wg, const float* __restrict__ Ug, const float* __restrict__ bg,
    const float* __restrict__ Wc, const float* __restrict__ Uc, const float* __restrict__ bc,
    int* __restrict__ len_g, u16* __restrict__ rnn1)
{
  __shared__ __attribute__((aligned(16))) u16 hbL[16][72];
  __shared__ __attribute__((aligned(16))) u16 pbL[16][72];
  __shared__ int lenL[16];
  const int tid=threadIdx.x;
  const int w=tid>>6, lane=tid&63, q=lane>>4, mm=lane&15;
  const int g=blockIdx.x, b0=g*16, pb_m=b0+mm;

  if (w==0){
    int cnt=0;
    for (int t=q*50;t<q*50+50;t++) cnt += (mask[(size_t)pb_m*TT+t]!=0.0f);
    cnt += __shfl_xor(cnt,16);
    cnt += __shfl_xor(cnt,32);
    if (lane<16){ lenL[lane]=cnt; len_g[b0+lane]=cnt; }
  }
  for (int ii=tid; ii<16*72; ii+=256) (&hbL[0][0])[ii]=0;
  __syncthreads();

  int lenq[4];
#pragma unroll
  for (int r=0;r<4;r++) lenq[r]=lenL[q*4+r];
  int maxlen=1;
  for (int i=0;i<16;i++) maxlen=(lenL[i]>maxlen)?lenL[i]:maxlen;

  const int nr=16*w+mm, nz=64+16*w+mm;
  s16x8 wgr[4], wgz[4], wcf[4];
#pragma unroll
  for (int c=0;c<4;c++){
    s16x8 fr,fz,fc;
#pragma unroll
    for (int j=0;j<8;j++){
      int k=32*c+q*8+j;
      fr[j]=(short)f2bf((k<64)?Wg[(size_t)k*128+nr]:Ug[(size_t)(k-64)*128+nr]);
      fz[j]=(short)f2bf((k<64)?Wg[(size_t)k*128+nz]:Ug[(size_t)(k-64)*128+nz]);
      fc[j]=(short)f2bf((k<64)?Wc[(size_t)k*64+nr]:Uc[(size_t)(k-64)*64+nr]);
    }
    wgr[c]=fr; wgz[c]=fz; wcf[c]=fc;
  }
  const float bgr=bg[nr], bgz=bg[nz], bcv=bc[nr];

  float hreg[4]={0.0f,0.0f,0.0f,0.0f};

  auto load_x=[&](int t, s16x8 &a0, s16x8 &a1){
    int idx = hist[(size_t)pb_m*TT+t];
    const u16* p=emb16+(size_t)idx*64;
    a0=*(const s16x8*)(p+q*8);
    a1=*(const s16x8*)(p+32+q*8);
  };

  s16x8 xf0,xf1;
  load_x(0,xf0,xf1);
  for (int t=0;t<maxlen;t++){
    s16x8 nx0,nx1;
    { int tn=(t+1<maxlen)?(t+1):(maxlen-1); load_x(tn,nx0,nx1); }

    s16x8 hb0=*(const s16x8*)&hbL[mm][q*8];
    s16x8 hb1=*(const s16x8*)&hbL[mm][32+q*8];

    f32x4 ar0={0.0f,0.0f,0.0f,0.0f}, ar1={0.0f,0.0f,0.0f,0.0f};
    f32x4 az0={0.0f,0.0f,0.0f,0.0f}, az1={0.0f,0.0f,0.0f,0.0f};
    ar0=MFMA16(xf0,wgr[0],ar0); az0=MFMA16(xf0,wgz[0],az0);
    ar0=MFMA16(xf1,wgr[1],ar0); az0=MFMA16(xf1,wgz[1],az0);
    ar1=MFMA16(hb0,wgr[2],ar1); az1=MFMA16(hb0,wgz[2],az1);
    ar1=MFMA16(hb1,wgr[3],ar1); az1=MFMA16(hb1,wgz[3],az1);
    f32x4 ar=ar0+ar1, az=az0+az1;

    float zs[4];
#pragma unroll
    for (int r=0;r<4;r++){
      float rg=sigm(ar[r]+bgr);
      pbL[q*4+r][16*w+mm]=f2bf(rg*hreg[r]);
      zs[r]=sigm(az[r]+bgz);
    }
    __syncthreads();

    s16x8 pb0=*(const s16x8*)&pbL[mm][q*8];
    s16x8 pb1=*(const s16x8*)&pbL[mm][32+q*8];

    f32x4 ac0={0.0f,0.0f,0.0f,0.0f}, ac1={0.0f,0.0f,0.0f,0.0f};
    ac0=MFMA16(xf0,wcf[0],ac0);
    ac0=MFMA16(xf1,wcf[1],ac0);
    ac1=MFMA16(pb0,wcf[2],ac1);
    ac1=MFMA16(pb1,wcf[3],ac1);
    f32x4 ac=ac0+ac1;
#pragma unroll
    for (int r=0;r<4;r++){
      float c=tanh_(ac[r]+bcv);
      float hn=zs[r]*hreg[r]+(1.0f-zs[r])*c;
      if (t>=lenq[r]) hn=hreg[r];
      hreg[r]=hn;
      u16 hh=f2bf(hn);
      hbL[q*4+r][16*w+mm]=hh;
      rnn1[((size_t)(b0+q*4+r)*TT+t)*64 + 16*w+mm]=hh;
    }
    __syncthreads();
    xf0=nx0; xf1=nx1;
  }
}

// ---------------- attn + fused softmax + attin=rnn1*alpha: 1 wave/row ----------------
__global__ __launch_bounds__(64,1) void attn_kernel(
    const int* __restrict__ iidx, const float* __restrict__ emb, const u16* __restrict__ rnn1,
    const float* __restrict__ Wa1, const float* __restrict__ ba1,
    const float* __restrict__ Wa2, const float* __restrict__ ba2,
    const float* __restrict__ Wa3, const float* __restrict__ ba3,
    const int* __restrict__ len_g, u16* __restrict__ attin)
{
  __shared__ __attribute__((aligned(16))) u16 d1buf[16][104];
  __shared__ float scS[208];
  const int lane=threadIdx.x, q=lane>>4, mm=lane&15;
  const int b=blockIdx.x;
  const int L=len_g[b];

  s16x8 w1k[5][2], wd[5][2];
#pragma unroll
  for (int nt=0;nt<5;nt++)
#pragma unroll
    for (int c=0;c<2;c++){
      s16x8 f1,f2;
#pragma unroll
      for (int j=0;j<8;j++){
        int k=32*c+q*8+j, n=16*nt+mm;
        f1[j]=(short)f2bf(Wa1[(size_t)(64+k)*80+n] - Wa1[(size_t)(128+k)*80+n]);
        f2[j]=(short)f2bf(Wa1[(size_t)(192+k)*80+n]);
      }
      w1k[nt][c]=f1; wd[nt][c]=f2;
    }
  s16x8 w2f[3][3];
#pragma unroll
  for (int nt=0;nt<3;nt++)
#pragma unroll
    for (int c=0;c<3;c++){
      s16x8 f;
#pragma unroll
      for (int j=0;j<8;j++){
        int k=32*c+q*8+j, n=16*nt+mm;
        f[j]=(short)((k<80 && n<40)?f2bf(Wa2[(size_t)k*40+n]):0);
      }
      w2f[nt][c]=f;
    }
  float ba2v[3], w3v[3];
#pragma unroll
  for (int nt=0;nt<3;nt++){ int n=16*nt+mm; ba2v[nt]=(n<40)?ba2[n]:0.0f; w3v[nt]=(n<40)?Wa3[n]:0.0f; }
  const float ba3v=ba3[0];

  const int ib=iidx[b];
  float qv0[8], qv1[8];
  s16x8 aq0,aq1;
#pragma unroll
  for (int j=0;j<8;j++){
    qv0[j]=emb[(size_t)ib*64+q*8+j];
    qv1[j]=emb[(size_t)ib*64+32+q*8+j];
    aq0[j]=(short)f2bf(qv0[j]); aq1[j]=(short)f2bf(qv1[j]);
  }
  float pre[5];
#pragma unroll
  for (int nt=0;nt<5;nt++){
    int n=16*nt+mm;
    s16x8 bp0,bp1;
#pragma unroll
    for (int j=0;j<8;j++){
      int k=q*8+j, k2=32+q*8+j;
      bp0[j]=(short)f2bf(Wa1[(size_t)k *80+n]+Wa1[(size_t)(128+k )*80+n]);
      bp1[j]=(short)f2bf(Wa1[(size_t)k2*80+n]+Wa1[(size_t)(128+k2)*80+n]);
    }
    f32x4 a={0.0f,0.0f,0.0f,0.0f};
    a=MFMA16(aq0,bp0,a); a=MFMA16(aq1,bp1,a);
    pre[nt]=a[0]+ba1[n];
  }

  for (int ii=lane; ii<16*104; ii+=64) (&d1buf[0][0])[ii]=0;
  for (int t=lane;t<208;t+=64) scS[t]=-1e9f;
  __syncthreads();

  const int nch=(L+15)>>4;
  for (int ch=0; ch<nch; ch++){
    int t0=ch*16;
    size_t base=((size_t)b*TT + t0+mm)*64;
    s16x8 kf0=*(const s16x8*)(rnn1+base+q*8);
    s16x8 kf1=*(const s16x8*)(rnn1+base+32+q*8);
    s16x8 kq0,kq1;
#pragma unroll
    for (int j=0;j<8;j++){
      kq0[j]=(short)f2bf(bf2f((u16)kf0[j])*qv0[j]);
      kq1[j]=(short)f2bf(bf2f((u16)kf1[j])*qv1[j]);
    }
    f32x4 acc[5];
#pragma unroll
    for (int nt=0;nt<5;nt++){
      f32x4 a={pre[nt],pre[nt],pre[nt],pre[nt]};
      a=MFMA16(kf0,w1k[nt][0],a); a=MFMA16(kf1,w1k[nt][1],a);
      a=MFMA16(kq0,wd[nt][0],a);  a=MFMA16(kq1,wd[nt][1],a);
      acc[nt]=a;
    }
#pragma unroll
    for (int nt=0;nt<5;nt++)
#pragma unroll
      for (int r=0;r<4;r++)
        d1buf[q*4+r][16*nt+mm]=f2bf(sigm(acc[nt][r]));
    __syncthreads();
    s16x8 a0=*(const s16x8*)&d1buf[mm][q*8];
    s16x8 a1=*(const s16x8*)&d1buf[mm][32+q*8];
    s16x8 a2=*(const s16x8*)&d1buf[mm][64+q*8];
    f32x4 acc2[3];
#pragma unroll
    for (int nt=0;nt<3;nt++){
      f32x4 a={0.0f,0.0f,0.0f,0.0f};
      a=MFMA16(a0,w2f[nt][0],a); a=MFMA16(a1,w2f[nt][1],a); a=MFMA16(a2,w2f[nt][2],a);
      acc2[nt]=a;
    }
    float part[4];
#pragma unroll
    for (int r=0;r<4;r++){
      float s=0.0f;
#pragma unroll
      for (int nt=0;nt<3;nt++) s+=sigm(acc2[nt][r]+ba2v[nt])*w3v[nt];
      part[r]=s;
    }
#pragma unroll
    for (int d=1;d<16;d<<=1)
#pragma unroll
      for (int r=0;r<4;r++) part[r]+=__shfl_xor(part[r],d);
    if (mm==0){
#pragma unroll
      for (int r=0;r<4;r++){ int t=t0+q*4+r; scS[t]=(t<L)?(part[r]+ba3v):-1e9f; }
    }
    __syncthreads();
  }

  // masked softmax
  float mx=-3e38f;
  for (int t=lane;t<TT;t+=64) mx=fmaxf(mx,scS[t]);
#pragma unroll
  for (int d=1;d<64;d<<=1) mx=fmaxf(mx,__shfl_xor(mx,d));
  float sm=0.0f;
  for (int t=lane;t<TT;t+=64) sm+=__expf(scS[t]-mx);
#pragma unroll
  for (int d=1;d<64;d<<=1) sm+=__shfl_xor(sm,d);
  float inv=1.0f/sm;

  // attin = rnn1 * alpha (bf16). alpha=0 past L kills stale rnn1.
  {
    int toff=lane>>3, cg=(lane&7)*8;
    for (int t0=0;t0<TT;t0+=8){
      int tt=t0+toff;
      float al=(tt<L)?(__expf(scS[tt]-mx)*inv):0.0f;
      size_t base=((size_t)b*TT+tt)*64+cg;
      u16x8 kk=*(const u16x8*)(rnn1+base);
      s16x8 o;
#pragma unroll
      for (int j=0;j<8;j++) o[j]=(short)f2bf(bf2f(kk[j])*al);
      *(s16x8*)(attin+base)=o;
    }
  }
}

// ---------------- scan2: gru2, 16 rows/block, pure-bf16 operands, x = attin ----------------
__global__ __launch_bounds__(256,1) void scan2_kernel(
    const u16* __restrict__ attin, const int* __restrict__ len_g,
    const float* __restrict__ Wg, const float* __restrict__ Ug, const float* __restrict__ bg,
    const float* __restrict__ Wc, const float* __restrict__ Uc, const float* __restrict__ bc,
    float* __restrict__ f2)
{
  __shared__ __attribute__((aligned(16))) u16 hbL[16][72];
  __shared__ __attribute__((aligned(16))) u16 pbL[16][72];
  __shared__ int lenL[16];
  const int tid=threadIdx.x;
  const int w=tid>>6, lane=tid&63, q=lane>>4, mm=lane&15;
  const int g=blockIdx.x, b0=g*16, pb_m=b0+mm;

  if (tid<16) lenL[tid]=len_g[b0+tid];
  for (int ii=tid; ii<16*72; ii+=256) (&hbL[0][0])[ii]=0;
  __syncthreads();

  int lenq[4];
#pragma unroll
  for (int r=0;r<4;r++) lenq[r]=lenL[q*4+r];
  int maxlen=1;
  for (int i=0;i<16;i++) maxlen=(lenL[i]>maxlen)?lenL[i]:maxlen;

  const int nr=16*w+mm, nz=64+16*w+mm;
  s16x8 wgr[4], wgz[4], wcf[4];
#pragma unroll
  for (int c=0;c<4;c++){
    s16x8 fr,fz,fc;
#pragma unroll
    for (int j=0;j<8;j++){
      int k=32*c+q*8+j;
      fr[j]=(short)f2bf((k<64)?Wg[(size_t)k*128+nr]:Ug[(size_t)(k-64)*128+nr]);
      fz[j]=(short)f2bf((k<64)?Wg[(size_t)k*128+nz]:Ug[(size_t)(k-64)*128+nz]);
      fc[j]=(short)f2bf((k<64)?Wc[(size_t)k*64+nr]:Uc[(size_t)(k-64)*64+nr]);
    }
    wgr[c]=fr; wgz[c]=fz; wcf[c]=fc;
  }
  const float bgr=bg[nr], bgz=bg[nz], bcv=bc[nr];

  float hreg[4]={0.0f,0.0f,0.0f,0.0f};

  auto load_x=[&](int t, s16x8 &a0, s16x8 &a1){
    size_t base=((size_t)pb_m*TT+t)*64;
    a0=*(const s16x8*)(attin+base+q*8);
    a1=*(const s16x8*)(attin+base+32+q*8);
  };

  s16x8 xf0,xf1;
  load_x(0,xf0,xf1);
  for (int t=0;t<maxlen;t++){
    s16x8 nx0,nx1;
    { int tn=(t+1<maxlen)?(t+1):(maxlen-1); load_x(tn,nx0,nx1); }

    s16x8 hb0=*(const s16x8*)&hbL[mm][q*8];
    s16x8 hb1=*(const s16x8*)&hbL[mm][32+q*8];

    f32x4 ar0={0.0f,0.0f,0.0f,0.0f}, ar1={0.0f,0.0f,0.0f,0.0f};
    f32x4 az0={0.0f,0.0f,0.0f,0.0f}, az1={0.0f,0.0f,0.0f,0.0f};
    ar0=MFMA16(xf0,wgr[0],ar0); az0=MFMA16(xf0,wgz[0],az0);
    ar0=MFMA16(xf1,wgr[1],ar0); az0=MFMA16(xf1,wgz[1],az0);
    ar1=MFMA16(hb0,wgr[2],ar1); az1=MFMA16(hb0,wgz[2],az1);
    ar1=MFMA16(hb1,wgr[3],ar1); az1=MFMA16(hb1,wgz[3],az1);
    f32x4 ar=ar0+ar1, az=az0+az1;

    float zs[4];
#pragma unroll
    for (int r=0;r<4;r++){
      float rg=sigm(ar[r]+bgr);
      pbL[q*4+r][16*w+mm]=f2bf(rg*hreg[r]);
      zs[r]=sigm(az[r]+bgz);
    }
    __syncthreads();

    s16x8 pb0=*(const s16x8*)&pbL[mm][q*8];
    s16x8 pb1=*(const s16x8*)&pbL[mm][32+q*8];

    f32x4 ac0={0.0f,0.0f,0.0f,0.0f}, ac1={0.0f,0.0f,0.0f,0.0f};
    ac0=MFMA16(xf0,wcf[0],ac0);
    ac0=MFMA16(xf1,wcf[1],ac0);
    ac1=MFMA16(pb0,wcf[2],ac1);
    ac1=MFMA16(pb1,wcf[3],ac1);
    f32x4 ac=ac0+ac1;
#pragma unroll
    for (int r=0;r<4;r++){
      float c=tanh_(ac[r]+bcv);
      float hn=zs[r]*hreg[r]+(1.0f-zs[r])*c;
      if (t>=lenq[r]) hn=hreg[r];
      hreg[r]=hn;
      hbL[q*4+r][16*w+mm]=f2bf(hn);
    }
    __syncthreads();
    xf0=nx0; xf1=nx1;
  }

#pragma unroll
  for (int r=0;r<4;r++)
    f2[(size_t)(b0+q*4+r)*64 + 16*w+mm]=hreg[r];
}

// ---------------- fcn: [ue|ie|hs|ie*hs|f2] (320) -> 128 -> 40 -> 1 ----------------
__global__ __launch_bounds__(64,1) void fcn_kernel(
    const int* __restrict__ uidx, const int* __restrict__ iidx,
    const float* __restrict__ uemb, const float* __restrict__ emb,
    const float* __restrict__ hs, const float* __restrict__ f2,
    const float* __restrict__ Wf1, const float* __restrict__ fb1, const float* __restrict__ fp1,
    const float* __restrict__ Wf2, const float* __restrict__ fb2, const float* __restrict__ fp2,
    const float* __restrict__ Wf3, const float* __restrict__ fb3,
    float* __restrict__ out)
{
  __shared__ float inL[16][320];
  __shared__ __attribute__((aligned(16))) u16 h1L[16][128];
  __shared__ float h2o[16][40];
  const int lane=threadIdx.x, q=lane>>4, mm=lane&15;
  const int b0=blockIdx.x*16;

  {
    int row=lane>>2, sub=lane&3;
    int b=b0+row;
    int ub=uidx[b], ibv=iidx[b];
    for (int c=sub*80;c<sub*80+80;c++){
      int seg=c>>6, f=c&63; float v;
      if      (seg==0) v=uemb[(size_t)ub*64+f];
      else if (seg==1) v=emb[(size_t)ibv*64+f];
      else if (seg==2) v=hs[(size_t)b*64+f];
      else if (seg==3) v=emb[(size_t)ibv*64+f]*hs[(size_t)b*64+f];
      else             v=f2[(size_t)b*64+f];
      inL[row][c]=v;
    }
  }
  __syncthreads();

  {
    f32x4 acc1[8];
#pragma unroll
    for (int nt=0;nt<8;nt++) acc1[nt]=f32x4{0.0f,0.0f,0.0f,0.0f};
#pragma unroll
    for (int kc=0;kc<10;kc++){
      s16x8 af;
#pragma unroll
      for (int j=0;j<8;j++) af[j]=(short)f2bf(inL[mm][32*kc+q*8+j]);
#pragma unroll
      for (int nt=0;nt<8;nt++){
        s16x8 bfr;
#pragma unroll
        for (int j=0;j<8;j++) bfr[j]=(short)f2bf(Wf1[(size_t)(32*kc+q*8+j)*128 + 16*nt+mm]);
        acc1[nt]=MFMA16(af,bfr,acc1[nt]);
      }
    }
#pragma unroll
    for (int nt=0;nt<8;nt++)
#pragma unroll
      for (int r=0;r<4;r++){
        int col=16*nt+mm, row=q*4+r;
        float x=acc1[nt][r]+fb1[col];
        float pp=fp1[col];
        h1L[row][col]=f2bf((x>=0.0f)?x:pp*x);
      }
  }
  __syncthreads();

  {
    f32x4 acc2[3];
#pragma unroll
    for (int nt=0;nt<3;nt++) acc2[nt]=f32x4{0.0f,0.0f,0.0f,0.0f};
#pragma unroll
    for (int kc=0;kc<4;kc++){
      s16x8 af=*(const s16x8*)&h1L[mm][32*kc+q*8];
#pragma unroll
      for (int nt=0;nt<3;nt++){
        s16x8 bfr;
#pragma unroll
        for (int j=0;j<8;j++){
          int k=32*kc+q*8+j, n=16*nt+mm;
          bfr[j]=(short)((n<40)?f2bf(Wf2[(size_t)k*40+n]):0);
        }
        acc2[nt]=MFMA16(af,bfr,acc2[nt]);
      }
    }
#pragma unroll
    for (int nt=0;nt<3;nt++)
#pragma unroll
      for (int r=0;r<4;r++){
        int col=16*nt+mm, row=q*4+r;
        if (col<40){
          float x=acc2[nt][r]+fb2[col];
          float pp=fp2[col];
          h2o[row][col]=(x>=0.0f)?x:pp*x;
        }
      }
  }
  __syncthreads();

  {
    int row=lane>>2, sub=lane&3;
    float s=0.0f;
    for (int k=sub;k<40;k+=4) s+=h2o[row][k]*Wf3[k];
    s+=__shfl_xor(s,1); s+=__shfl_xor(s,2);
    if (sub==0) out[b0+row]=s+fb3[0];
  }
}

// ================================================================
// FALLBACK (zero workspace): the R4 mega kernel, f32 path proven
// ================================================================
template<bool F32>
__global__ __launch_bounds__(64,1) void dien_mega_kernel(
    const int* __restrict__ uidx, const int* __restrict__ iidx,
    const int* __restrict__ hist, const void* __restrict__ mask,
    const void* __restrict__ emb,  const void* __restrict__ uemb,
    const void* __restrict__ W1g, const void* __restrict__ U1g, const void* __restrict__ g1bg,
    const void* __restrict__ W1c, const void* __restrict__ U1c, const void* __restrict__ g1bc,
    const void* __restrict__ Wa1, const void* __restrict__ ba1,
    const void* __restrict__ Wa2, const void* __restrict__ ba2,
    const void* __restrict__ Wa3, const void* __restrict__ ba3,
    const void* __restrict__ W2g, const void* __restrict__ U2g, const void* __restrict__ g2bg,
    const void* __restrict__ W2c, const void* __restrict__ U2c, const void* __restrict__ g2bc,
    const void* __restrict__ Wf1, const void* __restrict__ fb1, const void* __restrict__ fp1,
    const void* __restrict__ Wf2, const void* __restrict__ fb2, const void* __restrict__ fp2,
    const void* __restrict__ Wf3, const void* __restrict__ fb3,
    void* __restrict__ outp)
{
  auto LF=[&](const void* p, size_t i)->float {
    return F32 ? ((const float*)p)[i] : bf2f(((const u16*)p)[i]);
  };
  auto LB=[&](const void* p, size_t i)->u16 {
    return F32 ? f2bf(((const float*)p)[i]) : ((const u16*)p)[i];
  };
  auto FR8=[&](const void* p, size_t off)->s16x8 {
    s16x8 f;
    if (F32){
      const float* pp=(const float*)p+off;
      f32x4 a=*(const f32x4*)pp, b=*(const f32x4*)(pp+4);
#pragma unroll
      for (int j=0;j<4;j++){ f[j]=(short)f2bf(a[j]); f[j+4]=(short)f2bf(b[j]); }
    } else {
      f=*(const s16x8*)((const u16*)p+off);
    }
    return f;
  };

  __shared__ float h1buf[16][68];
  __shared__ float h2buf[16][68];
  __shared__ float pbuf [16][68];
  __shared__ u16   d1buf[16][104];
  __shared__ u16   scL  [16][200];
  __shared__ float hsL  [16][64];
  __shared__ s16x8 u2gL [16][64];
  __shared__ s16x8 u2cL [ 8][64];
  __shared__ float h2o  [16][40];
  __shared__ u16   ueL  [16][64];
  __shared__ u16   ieL  [16][64];
  __shared__ int   lenL [16];

  const int lane=threadIdx.x, q=lane>>4, mm=lane&15;
  const int g=blockIdx.x, b0=g*16;
  const int pb_m=b0+mm;

  {
    int cnt=0;
    for (int t=q*50;t<q*50+50;t++) cnt += (LF(mask,(size_t)pb_m*TT+t)!=0.0f);
    cnt += __shfl_xor(cnt,16);
    cnt += __shfl_xor(cnt,32);
    if (lane<16) lenL[lane]=cnt;
  }
  __syncthreads();
  int lenq[4];
#pragma unroll
  for (int r=0;r<4;r++) lenq[r]=lenL[q*4+r];
  int maxlen=1;
  for (int i=0;i<16;i++) maxlen = (lenL[i]>maxlen)?lenL[i]:maxlen;

  s16x8 wgt[8][4];
#pragma unroll
  for (int nt=0;nt<8;nt++)
#pragma unroll
    for (int c=0;c<4;c++){
      s16x8 f;
#pragma unroll
      for (int j=0;j<8;j++){
        int k=32*c+q*8+j, n=16*nt+mm;
        f[j]=(short)((k<64)?LB(W1g,(size_t)k*128+n):LB(U1g,(size_t)(k-64)*128+n));
      }
      wgt[nt][c]=f;
    }
  s16x8 wct[4][4];
#pragma unroll
  for (int nt=0;nt<4;nt++)
#pragma unroll
    for (int c=0;c<4;c++){
      s16x8 f;
#pragma unroll
      for (int j=0;j<8;j++){
        int k=32*c+q*8+j, n=16*nt+mm;
        f[j]=(short)((k<64)?LB(W1c,(size_t)k*64+n):LB(U1c,(size_t)(k-64)*64+n));
      }
      wct[nt][c]=f;
    }
  float b1gv[8], b1cv[4];
#pragma unroll
  for (int nt=0;nt<8;nt++) b1gv[nt]=LF(g1bg,16*nt+mm);
#pragma unroll
  for (int nt=0;nt<4;nt++) b1cv[nt]=LF(g1bc,16*nt+mm);

  s16x8 w1k[5][2], wd[5][2];
#pragma unroll
  for (int nt=0;nt<5;nt++)
#pragma unroll
    for (int c=0;c<2;c++){
      s16x8 f1,f2;
#pragma unroll
      for (int j=0;j<8;j++){
        int k=32*c+q*8+j, n=16*nt+mm;
        f1[j]=(short)f2bf(LF(Wa1,(size_t)(64+k)*80+n) - LF(Wa1,(size_t)(128+k)*80+n));
        f2[j]=(short)LB(Wa1,(size_t)(192+k)*80+n);
      }
      w1k[nt][c]=f1; wd[nt][c]=f2;
    }
  s16x8 w2f[3][3];
#pragma unroll
  for (int nt=0;nt<3;nt++)
#pragma unroll
    for (int c=0;c<3;c++){
      s16x8 f;
#pragma unroll
      for (int j=0;j<8;j++){
        int k=32*c+q*8+j, n=16*nt+mm;
        f[j]=(short)((k<80 && n<40)?LB(Wa2,(size_t)k*40+n):0);
      }
      w2f[nt][c]=f;
    }
  float ba2v[3], w3v[3];
#pragma unroll
  for (int nt=0;nt<3;nt++){ int n=16*nt+mm; ba2v[nt]=(n<40)?LF(ba2,n):0.0f; w3v[nt]=(n<40)?LF(Wa3,n):0.0f; }
  const float ba3v=LF(ba3,0);

  const int ib=iidx[pb_m];
  const s16x8 qf0=FR8(emb,(size_t)ib*64+q*8);
  const s16x8 qf1=FR8(emb,(size_t)ib*64+32+q*8);

  f32x4 pre[5];
#pragma unroll
  for (int nt=0;nt<5;nt++){
    f32x4 a={0.0f,0.0f,0.0f,0.0f};
#pragma unroll
    for (int c=0;c<2;c++){
      s16x8 f;
#pragma unroll
      for (int j=0;j<8;j++){
        int k=32*c+q*8+j, n=16*nt+mm;
        f[j]=(short)f2bf(LF(Wa1,(size_t)k*80+n) + LF(Wa1,(size_t)(128+k)*80+n));
      }
      a=MFMA16((c==0)?qf0:qf1, f, a);
    }
    float bb=LF(ba1,16*nt+mm);
#pragma unroll
    for (int r=0;r<4;r++) a[r]+=bb;
    pre[nt]=a;
  }

  for (int ii=lane; ii<16*68; ii+=64){ (&h1buf[0][0])[ii]=0.0f; (&h2buf[0][0])[ii]=0.0f; }
  for (int ii=lane; ii<16*104; ii+=64) (&d1buf[0][0])[ii]=0;
  __syncthreads();

  auto load_x=[&](int t, s16x8 &a0, s16x8 &a1){
    int idx = hist[(size_t)pb_m*TT+t];
    a0 = FR8(emb,(size_t)idx*64+q*8);
    a1 = FR8(emb,(size_t)idx*64+32+q*8);
  };

  float hsA[8], hsB[8];
#pragma unroll
  for (int j=0;j<8;j++){ hsA[j]=0.0f; hsB[j]=0.0f; }

  s16x8 xf0,xf1;
  load_x(0,xf0,xf1);
  for (int t=0;t<maxlen;t++){
    s16x8 nx0,nx1;
    { int tn=(t+1<maxlen)?(t+1):(maxlen-1); load_x(tn,nx0,nx1); }

#pragma unroll
    for (int j=0;j<8;j++){ hsA[j]+=bf2f((u16)xf0[j]); hsB[j]+=bf2f((u16)xf1[j]); }

    f32x4 hA0=*(const f32x4*)&h1buf[mm][q*8];
    f32x4 hA1=*(const f32x4*)&h1buf[mm][q*8+4];
    f32x4 hB0=*(const f32x4*)&h1buf[mm][32+q*8];
    f32x4 hB1=*(const f32x4*)&h1buf[mm][32+q*8+4];
    s16x8 hhi0,hlo0,hhi1,hlo1;
    split8(hA0,hA1,hhi0,hlo0);
    split8(hB0,hB1,hhi1,hlo1);

    f32x4 ga[8];
#pragma unroll
    for (int nt=0;nt<8;nt++){
      f32x4 a={0.0f,0.0f,0.0f,0.0f};
      a=MFMA16(xf0 ,wgt[nt][0],a);
      a=MFMA16(xf1 ,wgt[nt][1],a);
      a=MFMA16(hhi0,wgt[nt][2],a);
      a=MFMA16(hhi1,wgt[nt][3],a);
      a=MFMA16(hlo0,wgt[nt][2],a);
      a=MFMA16(hlo1,wgt[nt][3],a);
      ga[nt]=a;
    }
    float zs[4][4], hv[4][4];
#pragma unroll
    for (int nt=0;nt<4;nt++)
#pragma unroll
      for (int r=0;r<4;r++){
        float rg=sigm(ga[nt][r]+b1gv[nt]);
        float h_=h1buf[q*4+r][16*nt+mm];
        hv[nt][r]=h_;
        pbuf[q*4+r][16*nt+mm]=rg*h_;
        zs[nt][r]=sigm(ga[nt+4][r]+b1gv[nt+4]);
      }
    __syncthreads();

    f32x4 pA0=*(const f32x4*)&pbuf[mm][q*8];
    f32x4 pA1=*(const f32x4*)&pbuf[mm][q*8+4];
    f32x4 pB0=*(const f32x4*)&pbuf[mm][32+q*8];
    f32x4 pB1=*(const f32x4*)&pbuf[mm][32+q*8+4];
    s16x8 phi0,plo0,phi1,plo1;
    split8(pA0,pA1,phi0,plo0);
    split8(pB0,pB1,phi1,plo1);

    f32x4 ca[4];
#pragma unroll
    for (int nt=0;nt<4;nt++){
      f32x4 a={0.0f,0.0f,0.0f,0.0f};
      a=MFMA16(xf0 ,wct[nt][0],a);
      a=MFMA16(xf1 ,wct[nt][1],a);
      a=MFMA16(phi0,wct[nt][2],a);
      a=MFMA16(phi1,wct[nt][3],a);
      a=MFMA16(plo0,wct[nt][2],a);
      a=MFMA16(plo1,wct[nt][3],a);
      ca[nt]=a;
    }
#pragma unroll
    for (int nt=0;nt<4;nt++)
#pragma unroll
      for (int r=0;r<4;r++){
        float c=tanh_(ca[nt][r]+b1cv[nt]);
        float z=zs[nt][r];
        float hn=z*hv[nt][r]+(1.0f-z)*c;
        if (t>=lenq[r]) hn=hv[nt][r];
        h1buf[q*4+r][16*nt+mm]=hn;
      }
    __syncthreads();

    f32x4 k0a=*(const f32x4*)&h1buf[mm][q*8];
    f32x4 k0b=*(const f32x4*)&h1buf[mm][q*8+4];
    f32x4 k1a=*(const f32x4*)&h1buf[mm][32+q*8];
    f32x4 k1b=*(const f32x4*)&h1buf[mm][32+q*8+4];
    s16x8 kf0,kf1,kq0,kq1;
#pragma unroll
    for (int j=0;j<4;j++){
      kf0[j]  =(short)f2bf(k0a[j]);  kf0[j+4]=(short)f2bf(k0b[j]);
      kf1[j]  =(short)f2bf(k1a[j]);  kf1[j+4]=(short)f2bf(k1b[j]);
      kq0[j]  =(short)f2bf(k0a[j]*bf2f((u16)qf0[j]));
      kq0[j+4]=(short)f2bf(k0b[j]*bf2f((u16)qf0[j+4]));
      kq1[j]  =(short)f2bf(k1a[j]*bf2f((u16)qf1[j]));
      kq1[j+4]=(short)f2bf(k1b[j]*bf2f((u16)qf1[j+4]));
    }
    f32x4 acc[5];
#pragma unroll
    for (int nt=0;nt<5;nt++){
      f32x4 a=pre[nt];
      a=MFMA16(kf0,w1k[nt][0],a); a=MFMA16(kf1,w1k[nt][1],a);
      a=MFMA16(kq0,wd[nt][0],a);  a=MFMA16(kq1,wd[nt][1],a);
      acc[nt]=a;
    }
#pragma unroll
    for (int nt=0;nt<5;nt++)
#pragma unroll
      for (int r=0;r<4;r++)
        d1buf[q*4+r][16*nt+mm]=f2bf(sigm(acc[nt][r]));
    __syncthreads();
    s16x8 a0=*(const s16x8*)&d1buf[mm][q*8];
    s16x8 a1=*(const s16x8*)&d1buf[mm][32+q*8];
    s16x8 a2=*(const s16x8*)&d1buf[mm][64+q*8];
    f32x4 acc2[3];
#pragma unroll
    for (int nt=0;nt<3;nt++){
      f32x4 a={0.0f,0.0f,0.0f,0.0f};
      a=MFMA16(a0,w2f[nt][0],a); a=MFMA16(a1,w2f[nt][1],a); a=MFMA16(a2,w2f[nt][2],a);
      acc2[nt]=a;
    }
    float part[4];
#pragma unroll
    for (int r=0;r<4;r++){
      float sacc=0.0f;
#pragma unroll
      for (int nt=0;nt<3;nt++) sacc+=sigm(acc2[nt][r]+ba2v[nt])*w3v[nt];
      part[r]=sacc;
    }
#pragma unroll
    for (int d=1;d<16;d<<=1)
#pragma unroll
      for (int r=0;r<4;r++) part[r]+=__shfl_xor(part[r],d);
    if (mm==0){
#pragma unroll
      for (int r=0;r<4;r++) scL[q*4+r][t]=f2bf(part[r]+ba3v);
    }
    __syncthreads();

    xf0=nx0; xf1=nx1;
  }

  for (int t=maxlen;t<TT;t++){
    s16x8 a0,a1; load_x(t,a0,a1);
#pragma unroll
    for (int j=0;j<8;j++){ hsA[j]+=bf2f((u16)a0[j]); hsB[j]+=bf2f((u16)a1[j]); }
  }
#pragma unroll
  for (int j=0;j<8;j++){ hsL[mm][q*8+j]=hsA[j]; hsL[mm][32+q*8+j]=hsB[j]; }
  __syncthreads();

  {
    int row=lane>>2, sub=lane&3;
    int L=lenL[row];
    float mx=-3e38f;
    for (int t=sub;t<L;t+=4) mx=fmaxf(mx,bf2f(scL[row][t]));
    mx=fmaxf(mx,__shfl_xor(mx,1)); mx=fmaxf(mx,__shfl_xor(mx,2));
    float sm=0.0f;
    for (int t=sub;t<L;t+=4) sm+=__expf(bf2f(scL[row][t])-mx);
    sm+=__shfl_xor(sm,1); sm+=__shfl_xor(sm,2);
    float inv=1.0f/sm;
    for (int t=sub;t<TT;t+=4){
      float v=(t<L)?(__expf(bf2f(scL[row][t])-mx)*inv):0.0f;
      scL[row][t]=f2bf(v);
    }
  }
  __syncthreads();

  s16x8 wg2x[8][2], wc2x[4][2];
#pragma unroll
  for (int nt=0;nt<8;nt++)
#pragma unroll
    for (int c=0;c<2;c++){
      s16x8 f,fh;
#pragma unroll
      for (int j=0;j<8;j++){
        int k=32*c+q*8+j, n=16*nt+mm;
        f[j] =(short)LB(W2g,(size_t)k*128+n);
        fh[j]=(short)LB(U2g,(size_t)k*128+n);
      }
      wg2x[nt][c]=f;
      u2gL[nt*2+c][lane]=fh;
    }
#pragma unroll
  for (int nt=0;nt<4;nt++)
#pragma unroll
    for (int c=0;c<2;c++){
      s16x8 f,fh;
#pragma unroll
      for (int j=0;j<8;j++){
        int k=32*c+q*8+j, n=16*nt+mm;
        f[j] =(short)LB(W2c,(size_t)k*64+n);
        fh[j]=(short)LB(U2c,(size_t)k*64+n);
      }
      wc2x[nt][c]=f;
      u2cL[nt*2+c][lane]=fh;
    }
  float b2gv[8], b2cv[4];
#pragma unroll
  for (int nt=0;nt<8;nt++) b2gv[nt]=LF(g2bg,16*nt+mm);
#pragma unroll
  for (int nt=0;nt<4;nt++) b2cv[nt]=LF(g2bc,16*nt+mm);

  for (int ii=lane; ii<16*68; ii+=64){ (&h1buf[0][0])[ii]=0.0f; (&h2buf[0][0])[ii]=0.0f; }
  __syncthreads();

  load_x(0,xf0,xf1);
  for (int t=0;t<maxlen;t++){
    s16x8 nx0,nx1;
    { int tn=(t+1<maxlen)?(t+1):(maxlen-1); load_x(tn,nx0,nx1); }

    {
      f32x4 hA0=*(const f32x4*)&h1buf[mm][q*8];
      f32x4 hA1=*(const f32x4*)&h1buf[mm][q*8+4];
      f32x4 hB0=*(const f32x4*)&h1buf[mm][32+q*8];
      f32x4 hB1=*(const f32x4*)&h1buf[mm][32+q*8+4];
      s16x8 hhi0,hlo0,hhi1,hlo1;
      split8(hA0,hA1,hhi0,hlo0);
      split8(hB0,hB1,hhi1,hlo1);
      f32x4 ga[8];
#pragma unroll
      for (int nt=0;nt<8;nt++){
        f32x4 a={0.0f,0.0f,0.0f,0.0f};
        a=MFMA16(xf0 ,wgt[nt][0],a);
        a=MFMA16(xf1 ,wgt[nt][1],a);
        a=MFMA16(hhi0,wgt[nt][2],a);
        a=MFMA16(hhi1,wgt[nt][3],a);
        a=MFMA16(hlo0,wgt[nt][2],a);
        a=MFMA16(hlo1,wgt[nt][3],a);
        ga[nt]=a;
      }
      float zs[4][4], hv[4][4];
#pragma unroll
      for (int nt=0;nt<4;nt++)
#pragma unroll
        for (int r=0;r<4;r++){
          float rg=sigm(ga[nt][r]+b1gv[nt]);
          float h_=h1buf[q*4+r][16*nt+mm];
          hv[nt][r]=h_;
          pbuf[q*4+r][16*nt+mm]=rg*h_;
          zs[nt][r]=sigm(ga[nt+4][r]+b1gv[nt+4]);
        }
      __syncthreads();
      f32x4 pA0=*(const f32x4*)&pbuf[mm][q*8];
      f32x4 pA1=*(const f32x4*)&pbuf[mm][q*8+4];
      f32x4 pB0=*(const f32x4*)&pbuf[mm][32+q*8];
      f32x4 pB1=*(const f32x4*)&pbuf[mm][32+q*8+4];
      s16x8 phi0,plo0,phi1,plo1;
      split8(pA0,pA1,phi0,plo0);
      split8(pB0,pB1,phi1,plo1);
      f32x4 ca[4];
#pragma unroll
      for (int nt=0;nt<4;nt++){
        f32x4 a={0.0f,0.0f,0.0f,0.0f};
        a=MFMA16(xf0 ,wct[nt][0],a);
        a=MFMA16(xf1 ,wct[nt][1],a);
        a=MFMA16(phi0,wct[nt][2],a);
        a=MFMA16(phi1,wct[nt][3],a);
        a=MFMA16(plo0,wct[nt][2],a);
        a=MFMA16(plo1,wct[nt][3],a);
        ca[nt]=a;
      }
#pragma unroll
      for (int nt=0;nt<4;nt++)
#pragma unroll
        for (int r=0;r<4;r++){
          float c=tanh_(ca[nt][r]+b1cv[nt]);
          float z=zs[nt][r];
          float hn=z*hv[nt][r]+(1.0f-z)*c;
          if (t>=lenq[r]) hn=hv[nt][r];
          h1buf[q*4+r][16*nt+mm]=hn;
        }
      __syncthreads();
    }

    {
      float al=bf2f(scL[mm][t]);
      f32x4 x0a=*(const f32x4*)&h1buf[mm][q*8];
      f32x4 x0b=*(const f32x4*)&h1buf[mm][q*8+4];
      f32x4 x1a=*(const f32x4*)&h1buf[mm][32+q*8];
      f32x4 x1b=*(const f32x4*)&h1buf[mm][32+q*8+4];
      s16x8 af0,af1;
#pragma unroll
      for (int j=0;j<4;j++){
        af0[j]  =(short)f2bf(x0a[j]*al); af0[j+4]=(short)f2bf(x0b[j]*al);
        af1[j]  =(short)f2bf(x1a[j]*al); af1[j+4]=(short)f2bf(x1b[j]*al);
      }
      f32x4 hA0=*(const f32x4*)&h2buf[mm][q*8];
      f32x4 hA1=*(const f32x4*)&h2buf[mm][q*8+4];
      f32x4 hB0=*(const f32x4*)&h2buf[mm][32+q*8];
      f32x4 hB1=*(const f32x4*)&h2buf[mm][32+q*8+4];
      s16x8 hhi0,hlo0,hhi1,hlo1;
      split8(hA0,hA1,hhi0,hlo0);
      split8(hB0,hB1,hhi1,hlo1);
      f32x4 ga[8];
#pragma unroll
      for (int nt=0;nt<8;nt++){
        s16x8 wh0=u2gL[nt*2+0][lane];
        s16x8 wh1=u2gL[nt*2+1][lane];
        f32x4 a={0.0f,0.0f,0.0f,0.0f};
        a=MFMA16(af0 ,wg2x[nt][0],a);
        a=MFMA16(af1 ,wg2x[nt][1],a);
        a=MFMA16(hhi0,wh0,a);
        a=MFMA16(hhi1,wh1,a);
        a=MFMA16(hlo0,wh0,a);
        a=MFMA16(hlo1,wh1,a);
        ga[nt]=a;
      }
      float zs[4][4], hv[4][4];
#pragma unroll
      for (int nt=0;nt<4;nt++)
#pragma unroll
        for (int r=0;r<4;r++){
          float rg=sigm(ga[nt][r]+b2gv[nt]);
          float h_=h2buf[q*4+r][16*nt+mm];
          hv[nt][r]=h_;
          pbuf[q*4+r][16*nt+mm]=rg*h_;
          zs[nt][r]=sigm(ga[nt+4][r]+b2gv[nt+4]);
        }
      __syncthreads();
      f32x4 pA0=*(const f32x4*)&pbuf[mm][q*8];
      f32x4 pA1=*(const f32x4*)&pbuf[mm][q*8+4];
      f32x4 pB0=*(const f32x4*)&pbuf[mm][32+q*8];
      f32x4 pB1=*(const f32x4*)&pbuf[mm][32+q*8+4];
      s16x8 phi0,plo0,phi1,plo1;
      split8(pA0,pA1,phi0,plo0);
      split8(pB0,pB1,phi1,plo1);
      f32x4 ca[4];
#pragma unroll
      for (int nt=0;nt<4;nt++){
        s16x8 wh0=u2cL[nt*2+0][lane];
        s16x8 wh1=u2cL[nt*2+1][lane];
        f32x4 a={0.0f,0.0f,0.0f,0.0f};
        a=MFMA16(af0 ,wc2x[nt][0],a);
        a=MFMA16(af1 ,wc2x[nt][1],a);
        a=MFMA16(phi0,wh0,a);
        a=MFMA16(phi1,wh1,a);
        a=MFMA16(plo0,wh0,a);
        a=MFMA16(plo1,wh1,a);
        ca[nt]=a;
      }
#pragma unroll
      for (int nt=0;nt<4;nt++)
#pragma unroll
        for (int r=0;r<4;r++){
          float c=tanh_(ca[nt][r]+b2cv[nt]);
          float z=zs[nt][r];
          float hn=z*hv[nt][r]+(1.0f-z)*c;
          if (t>=lenq[r]) hn=hv[nt][r];
          h2buf[q*4+r][16*nt+mm]=hn;
        }
      __syncthreads();
    }

    xf0=nx0; xf1=nx1;
  }

  {
    int row=lane>>2, c0=(lane&3)*16;
    int ub=uidx[b0+row], ibv=iidx[b0+row];
#pragma unroll
    for (int j=0;j<16;j++){
      ueL[row][c0+j]=LB(uemb,(size_t)ub*64+c0+j);
      ieL[row][c0+j]=LB(emb ,(size_t)ibv*64+c0+j);
    }
  }
  __syncthreads();

  {
    f32x4 acc1[8];
#pragma unroll
    for (int nt=0;nt<8;nt++) acc1[nt]=f32x4{0.0f,0.0f,0.0f,0.0f};
#pragma unroll
    for (int kc=0;kc<10;kc++){
      const int seg=kc>>1, off=(kc&1)*32+q*8;
      s16x8 af;
#pragma unroll
      for (int j=0;j<8;j++){
        int f=off+j;
        u16 v;
        if      (seg==0) v=ueL[mm][f];
        else if (seg==1) v=ieL[mm][f];
        else if (seg==2) v=f2bf(hsL[mm][f]);
        else if (seg==3) v=f2bf(bf2f(ieL[mm][f])*hsL[mm][f]);
        else             v=f2bf(h2buf[mm][f]);
        af[j]=(short)v;
      }
#pragma unroll
      for (int nt=0;nt<8;nt++){
        s16x8 bfr;
#pragma unroll
        for (int j=0;j<8;j++) bfr[j]=(short)LB(Wf1,(size_t)(32*kc+q*8+j)*128 + 16*nt+mm);
        acc1[nt]=MFMA16(af,bfr,acc1[nt]);
      }
    }
    __syncthreads();
#pragma unroll
    for (int nt=0;nt<8;nt++)
#pragma unroll
      for (int r=0;r<4;r++){
        int col=16*nt+mm, row=q*4+r;
        float x=acc1[nt][r]+LF(fb1,col);
        float pp=LF(fp1,col);
        scL[row][col]=f2bf((x>=0.0f)?x:pp*x);
      }
  }
  __syncthreads();

  {
    f32x4 acc2[3];
#pragma unroll
    for (int nt=0;nt<3;nt++) acc2[nt]=f32x4{0.0f,0.0f,0.0f,0.0f};
#pragma unroll
    for (int kc=0;kc<4;kc++){
      s16x8 af=*(const s16x8*)&scL[mm][32*kc+q*8];
#pragma unroll
      for (int nt=0;nt<3;nt++){
        s16x8 bfr;
#pragma unroll
        for (int j=0;j<8;j++){
          int k=32*kc+q*8+j, n=16*nt+mm;
          bfr[j]=(short)((n<40)?LB(Wf2,(size_t)k*40+n):0);
        }
        acc2[nt]=MFMA16(af,bfr,acc2[nt]);
      }
    }
#pragma unroll
    for (int nt=0;nt<3;nt++)
#pragma unroll
      for (int r=0;r<4;r++){
        int col=16*nt+mm, row=q*4+r;
        if (col<40){
          float x=acc2[nt][r]+LF(fb2,col);
          float pp=LF(fp2,col);
          h2o[row][col]=(x>=0.0f)?x:pp*x;
        }
      }
  }
  __syncthreads();

  {
    int row=lane>>2, sub=lane&3;
    float s=0.0f;
    for (int k=sub;k<40;k+=4) s+=h2o[row][k]*LF(Wf3,k);
    s+=__shfl_xor(s,1); s+=__shfl_xor(s,2);
    if (sub==0){
      float v=s+LF(fb3,0);
      if (F32) ((float*)outp)[b0+row]=v;
      else     ((u16*) outp)[b0+row]=f2bf(v);
    }
  }
}

extern "C" void kernel_launch(void* const* d_in, const int* in_sizes, int n_in,
                              void* d_out, int out_size, void* d_ws, size_t ws_size,
                              hipStream_t stream)
{
  (void)n_in; (void)out_size;
  const int* u    =(const int*)d_in[0];
  const int* it   =(const int*)d_in[1];
  const int* hist =(const int*)d_in[2];
  const float* mask=(const float*)d_in[3];
  const float* item_emb=(const float*)d_in[4];
  const float* user_emb=(const float*)d_in[5];
  const float* g1Wg=(const float*)d_in[6],  *g1Ug=(const float*)d_in[7],  *g1bg=(const float*)d_in[8];
  const float* g1Wc=(const float*)d_in[9],  *g1Uc=(const float*)d_in[10], *g1bc=(const float*)d_in[11];
  const float* Wa1=(const float*)d_in[12], *ba1=(const float*)d_in[13];
  const float* Wa2=(const float*)d_in[14], *ba2=(const float*)d_in[15];
  const float* Wa3=(const float*)d_in[16], *ba3=(const float*)d_in[17];
  const float* g2Wg=(const float*)d_in[18], *g2Ug=(const float*)d_in[19], *g2bg=(const float*)d_in[20];
  const float* g2Wc=(const float*)d_in[21], *g2Uc=(const float*)d_in[22], *g2bc=(const float*)d_in[23];
  const float* W1=(const float*)d_in[24], *b1=(const float*)d_in[25], *p1=(const float*)d_in[26];
  const float* W2=(const float*)d_in[27], *b2=(const float*)d_in[28], *p2=(const float*)d_in[29];
  const float* W3=(const float*)d_in[30], *b3=(const float*)d_in[31];

  const int emb_n = in_sizes[4];                       // N_ITEM*64
  const size_t sz_rnn1 =(size_t)BB*TT*64*2;
  const size_t sz_attin=(size_t)BB*TT*64*2;
  const size_t sz_emb16=(((size_t)emb_n*2)+255)&~(size_t)255;
  const size_t sz_len  =(((size_t)BB*4)+255)&~(size_t)255;
  const size_t sz_hs   =(size_t)BB*64*4;
  const size_t sz_f2   =(size_t)BB*64*4;
  const size_t NEED = sz_rnn1+sz_attin+sz_emb16+sz_len+sz_hs+sz_f2 + 1024;

  if (ws_size >= NEED){
    char* ws=(char*)d_ws;
    u16*   rnn1 =(u16*)ws;   ws+=sz_rnn1;
    u16*   attin=(u16*)ws;   ws+=sz_attin;
    u16*   emb16=(u16*)ws;   ws+=sz_emb16;
    int*   len_g=(int*)ws;   ws+=sz_len;
    float* hs   =(float*)ws; ws+=sz_hs;
    float* f2   =(float*)ws;

    conv_kernel    <<<(emb_n/8+255)/256,256,0,stream>>>(item_emb, emb16, emb_n);
    hist_sum_kernel<<<BB*8/256,256,0,stream>>>(hist, emb16, hs);
    scan1_kernel   <<<BB/16, 256, 0, stream>>>(hist, mask, emb16,
                                               g1Wg,g1Ug,g1bg,g1Wc,g1Uc,g1bc,
                                               len_g, rnn1);
    attn_kernel    <<<BB,     64, 0, stream>>>(it, item_emb, rnn1,
                                               Wa1,ba1,Wa2,ba2,Wa3,ba3,
                                               len_g, attin);
    scan2_kernel   <<<BB/16, 256, 0, stream>>>(attin, len_g,
                                               g2Wg,g2Ug,g2bg,g2Wc,g2Uc,g2bc,
                                               f2);
    fcn_kernel     <<<BB/16,  64, 0, stream>>>(u, it, user_emb, item_emb, hs, f2,
                                               W1,b1,p1,W2,b2,p2,W3,b3,
                                               (float*)d_out);
  } else {
    dien_mega_kernel<true><<<BB/16, 64, 0, stream>>>(
        u, it, hist, mask, item_emb, user_emb,
        g1Wg,g1Ug,g1bg,g1Wc,g1Uc,g1bc,
        Wa1,ba1,Wa2,ba2,Wa3,ba3,
        g2Wg,g2Ug,g2bg,g2Wc,g2Uc,g2bc,
        W1,b1,p1,W2,b2,p2,W3,b3,
        d_out);
  }
}